// Round 16
// baseline (521.040 us; speedup 1.0000x reference)
//
#include <hip/hip_runtime.h>
#include <math.h>

#define NTOK 768
#define CS   384
#define CZ   128
#define NH   12
#define INF_ 100000.0f
#define EPS_ 1e-8f

typedef unsigned int  uint32;

__device__ __forceinline__ uint32 bf16rn(float x) {
    uint32 u = __float_as_uint(x);
    return (u + 0x7fffu + ((u >> 16) & 1u)) >> 16;
}
__device__ __forceinline__ float bflo(uint32 u) { return __uint_as_float((u & 0xffffu) << 16); }
__device__ __forceinline__ float bfhi(uint32 u) { return __uint_as_float(u & 0xffff0000u); }

#define QK_SCALE 0.14433756729740643f   // sqrt(1/48)
#define B_SCALE  0.5773502691896258f    // sqrt(1/3)
#define HW_SCALE 0.13608276348795434f   // sqrt(1/54)

// ---------------------------------------------------------------------------
// K1a: tiled GEMM. RAW[col][tok] = sum_k s[tok][k] * Wcat[k][col]  (no bias).
// ---------------------------------------------------------------------------
__global__ __launch_bounds__(256) void k1a_gemm(
    const float* __restrict__ s,
    const float* __restrict__ wq, const float* __restrict__ wkv,
    const float* __restrict__ wqp, const float* __restrict__ wkvp,
    float* __restrict__ RAW)
{
    __shared__ float sA[32][72];   // [k][m]
    __shared__ float sB[32][72];   // [k][n]
    const int tid  = threadIdx.x;
    const int tok0 = blockIdx.x * 64;
    const int col0 = blockIdx.y * 64;

    const int m0 = (tid & 15) * 4;
    const int n0 = (tid >> 4) * 4;

    float4 acc[4];
    #pragma unroll
    for (int nn = 0; nn < 4; nn++) acc[nn] = make_float4(0.f, 0.f, 0.f, 0.f);

    const int lam = tid >> 2, lak = (tid & 3) * 8;
    const int lbk = tid >> 3, lbc = (tid & 7) * 8;
    const int gcol = col0 + lbc;
    const float* wsrc; int wwidth, woff;
    if (gcol < 192)      { wsrc = wq;   wwidth = 192; woff = gcol; }
    else if (gcol < 576) { wsrc = wkv;  wwidth = 384; woff = gcol - 192; }
    else if (gcol < 720) { wsrc = wqp;  wwidth = 144; woff = gcol - 576; }
    else                 { wsrc = wkvp; wwidth = 432; woff = gcol - 720; }

    for (int kb = 0; kb < CS; kb += 32) {
        const float4 a0 = *(const float4*)&s[(tok0 + lam) * CS + kb + lak];
        const float4 a1 = *(const float4*)&s[(tok0 + lam) * CS + kb + lak + 4];
        const float4 b0 = *(const float4*)&wsrc[(size_t)(kb + lbk) * wwidth + woff];
        const float4 b1 = *(const float4*)&wsrc[(size_t)(kb + lbk) * wwidth + woff + 4];
        __syncthreads();
        sA[lak + 0][lam] = a0.x; sA[lak + 1][lam] = a0.y;
        sA[lak + 2][lam] = a0.z; sA[lak + 3][lam] = a0.w;
        sA[lak + 4][lam] = a1.x; sA[lak + 5][lam] = a1.y;
        sA[lak + 6][lam] = a1.z; sA[lak + 7][lam] = a1.w;
        *(float4*)&sB[lbk][lbc]     = b0;
        *(float4*)&sB[lbk][lbc + 4] = b1;
        __syncthreads();
        #pragma unroll
        for (int k = 0; k < 32; k++) {
            const float4 av = *(const float4*)&sA[k][m0];
            const float4 bv = *(const float4*)&sB[k][n0];
            acc[0].x += av.x * bv.x; acc[0].y += av.y * bv.x; acc[0].z += av.z * bv.x; acc[0].w += av.w * bv.x;
            acc[1].x += av.x * bv.y; acc[1].y += av.y * bv.y; acc[1].z += av.z * bv.y; acc[1].w += av.w * bv.y;
            acc[2].x += av.x * bv.z; acc[2].y += av.y * bv.z; acc[2].z += av.z * bv.z; acc[2].w += av.w * bv.z;
            acc[3].x += av.x * bv.w; acc[3].y += av.y * bv.w; acc[3].z += av.z * bv.w; acc[3].w += av.w * bv.w;
        }
    }
    #pragma unroll
    for (int nn = 0; nn < 4; nn++)
        *(float4*)&RAW[(size_t)(col0 + n0 + nn) * NTOK + tok0 + m0] = acc[nn];
}

// ---------------------------------------------------------------------------
// K1b: bias + rigid transform + GEMM-operand packing for the logit GEMM.
// ---------------------------------------------------------------------------
__global__ __launch_bounds__(256) void k1b_finish(
    const float* __restrict__ RAW,
    const float* __restrict__ rot, const float* __restrict__ trans,
    const float* __restrict__ bq, const float* __restrict__ bkv,
    const float* __restrict__ bqp, const float* __restrict__ bkvp,
    const float* __restrict__ head_weights,
    float* __restrict__ VT, float* __restrict__ QP, float* __restrict__ VPT,
    float* __restrict__ AP, float* __restrict__ BP,
    float* __restrict__ RQN, float* __restrict__ CKN)
{
    __shared__ float hwS[NH];
    const int tid = threadIdx.x;
    const int t  = blockIdx.x * 16 + (tid & 15);
    const int wk = tid >> 4;                      // 16 walkers

    if (tid < NH) hwS[tid] = logf(1.0f + expf(head_weights[tid])) * HW_SCALE;

    float R[9], T3[3];
    #pragma unroll
    for (int x = 0; x < 9; x++) R[x] = rot[t * 9 + x];
    #pragma unroll
    for (int x = 0; x < 3; x++) T3[x] = trans[t * 3 + x];
    __syncthreads();

    // q -> AP (scaled)
    for (int col = wk; col < 192; col += 16) {
        const int h = col >> 4, c = col & 15;
        AP[(size_t)(h * 28 + c) * NTOK + t] = QK_SCALE * (RAW[(size_t)col * NTOK + t] + bq[col]);
    }
    // k -> BP, v -> VT
    for (int idx = wk; idx < 192; idx += 16) {
        const int h = idx >> 4, c = idx & 15;
        BP[(size_t)(h * 28 + c) * NTOK + t] = RAW[(size_t)(192 + h * 32 + c) * NTOK + t] + bkv[h * 32 + c];
        VT[idx * NTOK + t] = RAW[(size_t)(192 + h * 32 + 16 + c) * NTOK + t] + bkv[h * 32 + 16 + c];
    }
    // q points: pidx = h*4+p -> QP + AP (hw-scaled)
    for (int pidx = wk; pidx < 48; pidx += 16) {
        const int h = pidx >> 2, p = pidx & 3;
        const float r0 = RAW[(size_t)(576 + 0 * 48 + pidx) * NTOK + t] + bqp[0 * 48 + pidx];
        const float r1 = RAW[(size_t)(576 + 1 * 48 + pidx) * NTOK + t] + bqp[1 * 48 + pidx];
        const float r2 = RAW[(size_t)(576 + 2 * 48 + pidx) * NTOK + t] + bqp[2 * 48 + pidx];
        #pragma unroll
        for (int x = 0; x < 3; x++) {
            const float v = R[x*3+0]*r0 + R[x*3+1]*r1 + R[x*3+2]*r2 + T3[x];
            QP[t * 144 + pidx * 3 + x] = v;
            AP[(size_t)(h * 28 + 16 + p * 3 + x) * NTOK + t] = hwS[h] * v;
        }
    }
    // kv points: pidx = h*12+pp; pp<4 -> BP (kp), else -> VPT
    for (int pidx = wk; pidx < 144; pidx += 16) {
        const int h = pidx / 12, pp = pidx % 12;
        const float r0 = RAW[(size_t)(720 + 0 * 144 + pidx) * NTOK + t] + bkvp[0 * 144 + pidx];
        const float r1 = RAW[(size_t)(720 + 1 * 144 + pidx) * NTOK + t] + bkvp[1 * 144 + pidx];
        const float r2 = RAW[(size_t)(720 + 2 * 144 + pidx) * NTOK + t] + bkvp[2 * 144 + pidx];
        #pragma unroll
        for (int x = 0; x < 3; x++) {
            const float v = R[x*3+0]*r0 + R[x*3+1]*r1 + R[x*3+2]*r2 + T3[x];
            if (pp < 4) BP[(size_t)(h * 28 + 16 + pp * 3 + x) * NTOK + t] = v;
            else        VPT[((h * 8 + pp - 4) * 3 + x) * NTOK + t] = v;
        }
    }
    __syncthreads();
    // norms (per head, per token)
    if (wk < NH) {
        const int h = wk;
        float sq = 0.f, sk = 0.f;
        #pragma unroll
        for (int d = 0; d < 12; d++) {
            const float a = QP[t * 144 + h * 12 + d];
            sq += a * a;
            const float b = BP[(size_t)(h * 28 + 16 + d) * NTOK + t];
            sk += b * b;
        }
        RQN[h * NTOK + t] = -0.5f * hwS[h] * sq;
        CKN[h * NTOK + t] = -0.5f * hwS[h] * sk;
    }
}

// ---------------------------------------------------------------------------
// K2: z projection, register-blocked GEMM, 2 i-rows per block.
// Round-14 postmortem: weight group og*11 floats is unaligned -> 11x
// ds_read_b32 per kk = LDS-pipe-bound (~146us). Fix: wL padded [k][48],
// og in 0..3 owns 12 floats at 48B offsets -> 3x ds_read_b128; and the same
// weight read now feeds TWO i-rows (96 FMAs per 5 b128 reads).
// zs stride 268: 16B-aligned rows, transpose-write 2-way banks (free).
// ---------------------------------------------------------------------------
__global__ __launch_bounds__(256) void k2_zproj(
    const float* __restrict__ z, const float* __restrict__ wb, const float* __restrict__ bb,
    const float* __restrict__ wdz, const float* __restrict__ bdz,
    float* __restrict__ BBT, uint32* __restrict__ PZB)
{
    __shared__ float wL[CZ * 48];          // [k][48]: o<12 wb | o<44 wdz | pad
    __shared__ float zs[2][16][268];       // [i2][kk][j-local]
    const int tid = threadIdx.x;
    const int i0 = blockIdx.y * 2;
    const int j0 = blockIdx.x * 256;

    for (int idx = tid; idx < CZ * 48; idx += 256) {
        const int k = idx / 48, o = idx % 48;
        wL[idx] = (o < 12) ? wb[k * 12 + o] : ((o < 44) ? wdz[k * 32 + (o - 12)] : 0.f);
    }

    const int jq = tid & 63;               // j-quad
    const int og = tid >> 6;               // output group (wave-uniform), o = og*12+oo
    const int r0 = tid >> 2, c4 = tid & 3; // loader coords
    const float* zb0 = z + ((size_t)(i0 + 0) * NTOK + j0) * CZ;
    const float* zb1 = z + ((size_t)(i0 + 1) * NTOK + j0) * CZ;

    float4 acc0[12], acc1[12];
    #pragma unroll
    for (int oo = 0; oo < 12; oo++) {
        const int o = og * 12 + oo;
        const float b = (o < 12) ? bb[o] : ((o < 44) ? bdz[o - 12] : 0.f);
        acc0[oo] = make_float4(b, b, b, b);
        acc1[oo] = make_float4(b, b, b, b);
    }

    float4 pre0[4], pre1[4];
    #pragma unroll
    for (int w = 0; w < 4; w++) {
        pre0[w] = *(const float4*)&zb0[(size_t)(r0 + 64 * w) * CZ + c4 * 4];
        pre1[w] = *(const float4*)&zb1[(size_t)(r0 + 64 * w) * CZ + c4 * 4];
    }

    __syncthreads();                       // wL ready

    for (int kb = 0; kb < 8; kb++) {
        #pragma unroll
        for (int w = 0; w < 4; w++) {
            zs[0][c4 * 4 + 0][r0 + 64 * w] = pre0[w].x;
            zs[0][c4 * 4 + 1][r0 + 64 * w] = pre0[w].y;
            zs[0][c4 * 4 + 2][r0 + 64 * w] = pre0[w].z;
            zs[0][c4 * 4 + 3][r0 + 64 * w] = pre0[w].w;
            zs[1][c4 * 4 + 0][r0 + 64 * w] = pre1[w].x;
            zs[1][c4 * 4 + 1][r0 + 64 * w] = pre1[w].y;
            zs[1][c4 * 4 + 2][r0 + 64 * w] = pre1[w].z;
            zs[1][c4 * 4 + 3][r0 + 64 * w] = pre1[w].w;
        }
        __syncthreads();
        if (kb < 7) {
            #pragma unroll
            for (int w = 0; w < 4; w++) {
                pre0[w] = *(const float4*)&zb0[(size_t)(r0 + 64 * w) * CZ + (kb + 1) * 16 + c4 * 4];
                pre1[w] = *(const float4*)&zb1[(size_t)(r0 + 64 * w) * CZ + (kb + 1) * 16 + c4 * 4];
            }
        }
        #pragma unroll
        for (int kk = 0; kk < 16; kk++) {
            const float4 zv0 = *(const float4*)&zs[0][kk][jq * 4];
            const float4 zv1 = *(const float4*)&zs[1][kk][jq * 4];
            const float* wrow = &wL[(kb * 16 + kk) * 48 + og * 12];   // 48B-aligned
            #pragma unroll
            for (int oo = 0; oo < 12; oo++) {
                const float w = wrow[oo];
                acc0[oo].x += zv0.x * w; acc0[oo].y += zv0.y * w;
                acc0[oo].z += zv0.z * w; acc0[oo].w += zv0.w * w;
                acc1[oo].x += zv1.x * w; acc1[oo].y += zv1.y * w;
                acc1[oo].z += zv1.z * w; acc1[oo].w += zv1.w * w;
            }
        }
        __syncthreads();
    }

    // PZ outputs (12 <= o < 44): bf16 pairs of adjacent j, coalesced uint2
    #pragma unroll
    for (int oo = 0; oo < 12; oo++) {
        const int o = og * 12 + oo;
        if (o >= 12 && o < 44) {
            const int c = o - 12;
            uint2 p0, p1;
            p0.x = bf16rn(acc0[oo].x) | (bf16rn(acc0[oo].y) << 16);
            p0.y = bf16rn(acc0[oo].z) | (bf16rn(acc0[oo].w) << 16);
            p1.x = bf16rn(acc1[oo].x) | (bf16rn(acc1[oo].y) << 16);
            p1.y = bf16rn(acc1[oo].z) | (bf16rn(acc1[oo].w) << 16);
            *((uint2*)PZB + (size_t)((i0 + 0) * 32 + c) * 192 + (j0 >> 2) + jq) = p0;
            *((uint2*)PZB + (size_t)((i0 + 1) * 32 + c) * 192 + (j0 >> 2) + jq) = p1;
        }
    }
    // BBT (o < 12, owned by og==0): transpose via zs (dead now), coalesced out
    if (og == 0) {
        #pragma unroll
        for (int oo = 0; oo < 12; oo++) {
            zs[0][oo][jq * 4 + 0] = acc0[oo].x;
            zs[0][oo][jq * 4 + 1] = acc0[oo].y;
            zs[0][oo][jq * 4 + 2] = acc0[oo].z;
            zs[0][oo][jq * 4 + 3] = acc0[oo].w;
            zs[1][oo][jq * 4 + 0] = acc1[oo].x;
            zs[1][oo][jq * 4 + 1] = acc1[oo].y;
            zs[1][oo][jq * 4 + 2] = acc1[oo].z;
            zs[1][oo][jq * 4 + 3] = acc1[oo].w;
        }
    }
    __syncthreads();
    for (int idx = tid; idx < 2 * 12 * 64; idx += 256) {
        const int i2 = idx / 768, rem = idx % 768;
        const int o = rem >> 6, jl = rem & 63;
        *(float4*)&BBT[((size_t)(i0 + i2) * 12 + o) * NTOK + j0 + jl * 4] =
            *(const float4*)&zs[i2][o][jl * 4];
    }
}

// ---------------------------------------------------------------------------
// K3a: logit GEMM per head. LG[i][h][j] = AP_h[i].BP_h[j] + b_scale*BBT
//      + RQN[h][i] + CKN[h][j] + INF*(m_i*m_j - 1).  64x64 tiles, K=28.
// ---------------------------------------------------------------------------
__global__ __launch_bounds__(256) void k3a_logits(
    const float* __restrict__ AP, const float* __restrict__ BP,
    const float* __restrict__ RQN, const float* __restrict__ CKN,
    const float* __restrict__ BBT, const float* __restrict__ mask,
    float* __restrict__ LG)
{
    __shared__ float sA[28][64];
    __shared__ float sB[28][64];
    const int tid = threadIdx.x;
    const int j0 = blockIdx.x * 64;
    const int i0 = blockIdx.y * 64;
    const int h  = blockIdx.z;

    #pragma unroll
    for (int t = 0; t < 7; t++) {
        const int idx = tid + t * 256;
        const int row = idx >> 6, col = idx & 63;
        sA[row][col] = AP[(size_t)(h * 28 + row) * NTOK + i0 + col];
        sB[row][col] = BP[(size_t)(h * 28 + row) * NTOK + j0 + col];
    }
    __syncthreads();

    const int m0 = (tid & 15) * 4;   // i offset
    const int n0 = (tid >> 4) * 4;   // j offset

    float4 acc[4];   // acc[mm] = float4 over j
    #pragma unroll
    for (int mm = 0; mm < 4; mm++) acc[mm] = make_float4(0.f, 0.f, 0.f, 0.f);

    #pragma unroll
    for (int k = 0; k < 28; k++) {
        const float4 av = *(const float4*)&sA[k][m0];
        const float4 bv = *(const float4*)&sB[k][n0];
        acc[0].x += av.x * bv.x; acc[0].y += av.x * bv.y; acc[0].z += av.x * bv.z; acc[0].w += av.x * bv.w;
        acc[1].x += av.y * bv.x; acc[1].y += av.y * bv.y; acc[1].z += av.y * bv.z; acc[1].w += av.y * bv.w;
        acc[2].x += av.z * bv.x; acc[2].y += av.z * bv.y; acc[2].z += av.z * bv.z; acc[2].w += av.z * bv.w;
        acc[3].x += av.w * bv.x; acc[3].y += av.w * bv.y; acc[3].z += av.w * bv.z; acc[3].w += av.w * bv.w;
    }

    const float4 ck = *(const float4*)&CKN[h * NTOK + j0 + n0];
    const float4 mj = *(const float4*)&mask[j0 + n0];
    #pragma unroll
    for (int mm = 0; mm < 4; mm++) {
        const int gi = i0 + m0 + mm;
        const float rq = RQN[h * NTOK + gi];
        const float mi = mask[gi];
        const float4 bb = *(const float4*)&BBT[((size_t)gi * NH + h) * NTOK + j0 + n0];
        float4 o;
        o.x = acc[mm].x + B_SCALE * bb.x + rq + ck.x + INF_ * (mi * mj.x - 1.0f);
        o.y = acc[mm].y + B_SCALE * bb.y + rq + ck.y + INF_ * (mi * mj.y - 1.0f);
        o.z = acc[mm].z + B_SCALE * bb.z + rq + ck.z + INF_ * (mi * mj.z - 1.0f);
        o.w = acc[mm].w + B_SCALE * bb.w + rq + ck.w + INF_ * (mi * mj.w - 1.0f);
        *(float4*)&LG[((size_t)gi * NH + h) * NTOK + j0 + n0] = o;
    }
}

// ---------------------------------------------------------------------------
// K3b: per row i — load logits, softmax (wave=head), wave-cooperative sums.
// ---------------------------------------------------------------------------
__global__ __launch_bounds__(768) void k3b_attn(
    const float* __restrict__ LG,
    const float* __restrict__ VT, const float* __restrict__ VPT,
    const uint32* __restrict__ PZB,
    float* __restrict__ O, float* __restrict__ OPT, float* __restrict__ OPAIR)
{
    __shared__ float LB[NH][NTOK];      // logits -> probs in place
    const int i = blockIdx.x, tid = threadIdx.x;

    #pragma unroll
    for (int hh = 0; hh < NH; hh++)
        LB[hh][tid] = LG[((size_t)i * NH + hh) * NTOK + tid];
    __syncthreads();

    const int h = tid >> 6, l = tid & 63;   // wave w = head w (12 waves exactly)

    // softmax
    {
        float m = -3.0e38f;
        for (int jj = l; jj < NTOK; jj += 64) m = fmaxf(m, LB[h][jj]);
        #pragma unroll
        for (int off = 32; off >= 1; off >>= 1) m = fmaxf(m, __shfl_xor(m, off));
        float ssum = 0.0f;
        for (int jj = l; jj < NTOK; jj += 64) {
            const float e = __expf(LB[h][jj] - m);
            LB[h][jj] = e;
            ssum += e;
        }
        #pragma unroll
        for (int off = 32; off >= 1; off >>= 1) ssum += __shfl_xor(ssum, off);
        const float inv = 1.0f / ssum;
        for (int jj = l; jj < NTOK; jj += 64) LB[h][jj] *= inv;
    }
    __syncthreads();

    // wave-cooperative weighted sums (all loads coalesced)
    #pragma unroll 1
    for (int r = 0; r < 40; r++) {
        const float4* src = (r < 16) ? (const float4*)&VT[(h * 16 + r) * NTOK]
                                     : (const float4*)&VPT[(h * 24 + (r - 16)) * NTOK];
        const float4 v0 = src[l],       p0 = *(const float4*)&LB[h][l * 4];
        const float4 v1 = src[64 + l],  p1 = *(const float4*)&LB[h][256 + l * 4];
        const float4 v2 = src[128 + l], p2 = *(const float4*)&LB[h][512 + l * 4];
        float acc = p0.x*v0.x + p0.y*v0.y + p0.z*v0.z + p0.w*v0.w
                  + p1.x*v1.x + p1.y*v1.y + p1.z*v1.z + p1.w*v1.w
                  + p2.x*v2.x + p2.y*v2.y + p2.z*v2.z + p2.w*v2.w;
        #pragma unroll
        for (int off = 32; off >= 1; off >>= 1) acc += __shfl_xor(acc, off);
        if (l == 0) {
            if (r < 16) O[i * 192 + h * 16 + r] = acc;
            else        OPT[i * 288 + h * 24 + (r - 16)] = acc;
        }
    }
    // o_pair: 32 bf16 rows of PZB[i][c][j] (pairs of adjacent j per u32)
    #pragma unroll 1
    for (int c = 0; c < 32; c++) {
        const uint2* src = (const uint2*)PZB + (size_t)(i * 32 + c) * 192;
        float a = 0.f;
        #pragma unroll
        for (int it = 0; it < 3; it++) {
            const uint2 u = src[it * 64 + l];
            const float4 p = *(const float4*)&LB[h][it * 256 + l * 4];
            a += p.x * bflo(u.x) + p.y * bfhi(u.x)
               + p.z * bflo(u.y) + p.w * bfhi(u.y);
        }
        #pragma unroll
        for (int off = 32; off >= 1; off >>= 1) a += __shfl_xor(a, off);
        if (l == 0) OPAIR[i * 384 + h * 32 + c] = a;
    }
}

// ---------------------------------------------------------------------------
// K4: inverse rotation + norms + concat + final linear (8 tokens/block)
// ---------------------------------------------------------------------------
#define K4T 8
__global__ __launch_bounds__(256) void k4_out(
    const float* __restrict__ O, const float* __restrict__ OPT, const float* __restrict__ OPAIR,
    const float* __restrict__ rot, const float* __restrict__ trans,
    const float* __restrict__ wout, const float* __restrict__ bout,
    float* __restrict__ out)
{
    __shared__ float f[K4T][960];
    const int n0 = blockIdx.x * K4T, tid = threadIdx.x;

    for (int idx = tid; idx < K4T * 192; idx += 256) {
        const int t = idx / 192, k = idx % 192;
        f[t][k] = O[(n0 + t) * 192 + k];
    }
    for (int idx = tid; idx < K4T * 384; idx += 256) {
        const int t = idx / 384, k = idx % 384;
        f[t][576 + k] = OPAIR[(n0 + t) * 384 + k];
    }
    for (int idx = tid; idx < K4T * 96; idx += 256) {
        const int t = idx / 96, hp = idx % 96;
        const int n = n0 + t;
        const float vx = OPT[n * 288 + hp * 3 + 0] - trans[n * 3 + 0];
        const float vy = OPT[n * 288 + hp * 3 + 1] - trans[n * 3 + 1];
        const float vz = OPT[n * 288 + hp * 3 + 2] - trans[n * 3 + 2];
        const float o0 = rot[n*9+0]*vx + rot[n*9+3]*vy + rot[n*9+6]*vz;
        const float o1 = rot[n*9+1]*vx + rot[n*9+4]*vy + rot[n*9+7]*vz;
        const float o2 = rot[n*9+2]*vx + rot[n*9+5]*vy + rot[n*9+8]*vz;
        f[t][192 + hp] = o0;
        f[t][288 + hp] = o1;
        f[t][384 + hp] = o2;
        f[t][480 + hp] = sqrtf(o0*o0 + o1*o1 + o2*o2 + EPS_);
    }
    __syncthreads();

    for (int o = tid; o < 384; o += 256) {
        float acc[K4T];
        #pragma unroll
        for (int t = 0; t < K4T; t++) acc[t] = bout[o];
        for (int k = 0; k < 960; k++) {
            const float wv = wout[k * 384 + o];
            #pragma unroll
            for (int t = 0; t < K4T; t++) acc[t] += f[t][k] * wv;
        }
        #pragma unroll
        for (int t = 0; t < K4T; t++) out[(n0 + t) * 384 + o] = acc[t];
    }
}

// ---------------------------------------------------------------------------
extern "C" void kernel_launch(void* const* d_in, const int* in_sizes, int n_in,
                              void* d_out, int out_size, void* d_ws, size_t ws_size,
                              hipStream_t stream) {
    (void)in_sizes; (void)n_in; (void)out_size; (void)ws_size;
    const float* s     = (const float*)d_in[0];
    const float* z     = (const float*)d_in[1];
    const float* rot   = (const float*)d_in[2];
    const float* trans = (const float*)d_in[3];
    const float* mask  = (const float*)d_in[4];
    const float* wq    = (const float*)d_in[5];
    const float* bq    = (const float*)d_in[6];
    const float* wkv   = (const float*)d_in[7];
    const float* bkv   = (const float*)d_in[8];
    const float* wqp   = (const float*)d_in[9];
    const float* bqp   = (const float*)d_in[10];
    const float* wkvp  = (const float*)d_in[11];
    const float* bkvp  = (const float*)d_in[12];
    const float* wb    = (const float*)d_in[13];
    const float* bb    = (const float*)d_in[14];
    const float* wdz   = (const float*)d_in[15];
    const float* bdz   = (const float*)d_in[16];
    const float* hwts  = (const float*)d_in[17];
    const float* wout  = (const float*)d_in[18];
    const float* bout  = (const float*)d_in[19];
    float* out = (float*)d_out;

    float* ws = (float*)d_ws;
    float* Q     = ws;                       // 147456 (unused, kept for layout)
    float* KT    = Q     + 147456;           // 147456 (unused)
    float* VT    = KT    + 147456;           // 147456
    float* QP    = VT    + 147456;           // 110592
    float* KPT   = QP    + 110592;           // 110592 (unused)
    float* VPT   = KPT   + 110592;           // 221184
    float* O     = VPT   + 221184;           // 147456
    float* OPT   = O     + 147456;           // 221184
    float* OPAIR = OPT   + 221184;           // 294912
    float* BBT   = OPAIR + 294912;           // 7,077,888 floats (28.3 MB)
    uint32* PZB  = (uint32*)(BBT + 7077888); // 768*32*384 u32 (37.7 MB)
    float* AP    = BBT + 7077888 + 9437184;  // 12*28*768 = 258048
    float* BP    = AP  + 258048;             // 258048
    float* RQN   = BP  + 258048;             // 9216
    float* CKN   = RQN + 9216;               // 9216
    float* LG    = CKN + 9216;               // 7,077,888 floats (28.3 MB)
    float* RAW = BBT;   // aliases BBT: dead before k2 runs

    hipLaunchKernelGGL(k1a_gemm, dim3(NTOK / 64, 1152 / 64), dim3(256), 0, stream,
                       s, wq, wkv, wqp, wkvp, RAW);
    hipLaunchKernelGGL(k1b_finish, dim3(NTOK / 16), dim3(256), 0, stream,
                       RAW, rot, trans, bq, bkv, bqp, bkvp, hwts,
                       VT, QP, VPT, AP, BP, RQN, CKN);
    hipLaunchKernelGGL(k2_zproj, dim3(3, NTOK / 2), dim3(256), 0, stream,
                       z, wb, bb, wdz, bdz, BBT, PZB);
    hipLaunchKernelGGL(k3a_logits, dim3(NTOK / 64, NTOK / 64, NH), dim3(256), 0, stream,
                       AP, BP, RQN, CKN, BBT, mask, LG);
    hipLaunchKernelGGL(k3b_attn, dim3(NTOK), dim3(768), 0, stream,
                       LG, VT, VPT, PZB, O, OPT, OPAIR);
    hipLaunchKernelGGL(k4_out, dim3(NTOK / K4T), dim3(256), 0, stream,
                       O, OPT, OPAIR, rot, trans, wout, bout, out);
}

// Round 17
// 468.044 us; speedup vs baseline: 1.1132x; 1.1132x over previous
//
#include <hip/hip_runtime.h>
#include <math.h>

#define NTOK 768
#define CS   384
#define CZ   128
#define NH   12
#define INF_ 100000.0f
#define EPS_ 1e-8f

typedef unsigned int  uint32;

__device__ __forceinline__ uint32 bf16rn(float x) {
    uint32 u = __float_as_uint(x);
    return (u + 0x7fffu + ((u >> 16) & 1u)) >> 16;
}
__device__ __forceinline__ float bflo(uint32 u) { return __uint_as_float((u & 0xffffu) << 16); }
__device__ __forceinline__ float bfhi(uint32 u) { return __uint_as_float(u & 0xffff0000u); }

#define QK_SCALE 0.14433756729740643f   // sqrt(1/48)
#define B_SCALE  0.5773502691896258f    // sqrt(1/3)
#define HW_SCALE 0.13608276348795434f   // sqrt(1/54)

// ---------------------------------------------------------------------------
// K1a: tiled GEMM. RAW[col][tok] = sum_k s[tok][k] * Wcat[k][col]  (no bias).
// ---------------------------------------------------------------------------
__global__ __launch_bounds__(256) void k1a_gemm(
    const float* __restrict__ s,
    const float* __restrict__ wq, const float* __restrict__ wkv,
    const float* __restrict__ wqp, const float* __restrict__ wkvp,
    float* __restrict__ RAW)
{
    __shared__ float sA[32][72];   // [k][m]
    __shared__ float sB[32][72];   // [k][n]
    const int tid  = threadIdx.x;
    const int tok0 = blockIdx.x * 64;
    const int col0 = blockIdx.y * 64;

    const int m0 = (tid & 15) * 4;
    const int n0 = (tid >> 4) * 4;

    float4 acc[4];
    #pragma unroll
    for (int nn = 0; nn < 4; nn++) acc[nn] = make_float4(0.f, 0.f, 0.f, 0.f);

    const int lam = tid >> 2, lak = (tid & 3) * 8;
    const int lbk = tid >> 3, lbc = (tid & 7) * 8;
    const int gcol = col0 + lbc;
    const float* wsrc; int wwidth, woff;
    if (gcol < 192)      { wsrc = wq;   wwidth = 192; woff = gcol; }
    else if (gcol < 576) { wsrc = wkv;  wwidth = 384; woff = gcol - 192; }
    else if (gcol < 720) { wsrc = wqp;  wwidth = 144; woff = gcol - 576; }
    else                 { wsrc = wkvp; wwidth = 432; woff = gcol - 720; }

    for (int kb = 0; kb < CS; kb += 32) {
        const float4 a0 = *(const float4*)&s[(tok0 + lam) * CS + kb + lak];
        const float4 a1 = *(const float4*)&s[(tok0 + lam) * CS + kb + lak + 4];
        const float4 b0 = *(const float4*)&wsrc[(size_t)(kb + lbk) * wwidth + woff];
        const float4 b1 = *(const float4*)&wsrc[(size_t)(kb + lbk) * wwidth + woff + 4];
        __syncthreads();
        sA[lak + 0][lam] = a0.x; sA[lak + 1][lam] = a0.y;
        sA[lak + 2][lam] = a0.z; sA[lak + 3][lam] = a0.w;
        sA[lak + 4][lam] = a1.x; sA[lak + 5][lam] = a1.y;
        sA[lak + 6][lam] = a1.z; sA[lak + 7][lam] = a1.w;
        *(float4*)&sB[lbk][lbc]     = b0;
        *(float4*)&sB[lbk][lbc + 4] = b1;
        __syncthreads();
        #pragma unroll
        for (int k = 0; k < 32; k++) {
            const float4 av = *(const float4*)&sA[k][m0];
            const float4 bv = *(const float4*)&sB[k][n0];
            acc[0].x += av.x * bv.x; acc[0].y += av.y * bv.x; acc[0].z += av.z * bv.x; acc[0].w += av.w * bv.x;
            acc[1].x += av.x * bv.y; acc[1].y += av.y * bv.y; acc[1].z += av.z * bv.y; acc[1].w += av.w * bv.y;
            acc[2].x += av.x * bv.z; acc[2].y += av.y * bv.z; acc[2].z += av.z * bv.z; acc[2].w += av.w * bv.z;
            acc[3].x += av.x * bv.w; acc[3].y += av.y * bv.w; acc[3].z += av.z * bv.w; acc[3].w += av.w * bv.w;
        }
    }
    #pragma unroll
    for (int nn = 0; nn < 4; nn++)
        *(float4*)&RAW[(size_t)(col0 + n0 + nn) * NTOK + tok0 + m0] = acc[nn];
}

// ---------------------------------------------------------------------------
// K1b: bias + rigid transform + GEMM-operand packing for the logit GEMM.
// ---------------------------------------------------------------------------
__global__ __launch_bounds__(256) void k1b_finish(
    const float* __restrict__ RAW,
    const float* __restrict__ rot, const float* __restrict__ trans,
    const float* __restrict__ bq, const float* __restrict__ bkv,
    const float* __restrict__ bqp, const float* __restrict__ bkvp,
    const float* __restrict__ head_weights,
    float* __restrict__ VT, float* __restrict__ QP, float* __restrict__ VPT,
    float* __restrict__ AP, float* __restrict__ BP,
    float* __restrict__ RQN, float* __restrict__ CKN)
{
    __shared__ float hwS[NH];
    const int tid = threadIdx.x;
    const int t  = blockIdx.x * 16 + (tid & 15);
    const int wk = tid >> 4;                      // 16 walkers

    if (tid < NH) hwS[tid] = logf(1.0f + expf(head_weights[tid])) * HW_SCALE;

    float R[9], T3[3];
    #pragma unroll
    for (int x = 0; x < 9; x++) R[x] = rot[t * 9 + x];
    #pragma unroll
    for (int x = 0; x < 3; x++) T3[x] = trans[t * 3 + x];
    __syncthreads();

    // q -> AP (scaled)
    for (int col = wk; col < 192; col += 16) {
        const int h = col >> 4, c = col & 15;
        AP[(size_t)(h * 28 + c) * NTOK + t] = QK_SCALE * (RAW[(size_t)col * NTOK + t] + bq[col]);
    }
    // k -> BP, v -> VT
    for (int idx = wk; idx < 192; idx += 16) {
        const int h = idx >> 4, c = idx & 15;
        BP[(size_t)(h * 28 + c) * NTOK + t] = RAW[(size_t)(192 + h * 32 + c) * NTOK + t] + bkv[h * 32 + c];
        VT[idx * NTOK + t] = RAW[(size_t)(192 + h * 32 + 16 + c) * NTOK + t] + bkv[h * 32 + 16 + c];
    }
    // q points: pidx = h*4+p -> QP + AP (hw-scaled)
    for (int pidx = wk; pidx < 48; pidx += 16) {
        const int h = pidx >> 2, p = pidx & 3;
        const float r0 = RAW[(size_t)(576 + 0 * 48 + pidx) * NTOK + t] + bqp[0 * 48 + pidx];
        const float r1 = RAW[(size_t)(576 + 1 * 48 + pidx) * NTOK + t] + bqp[1 * 48 + pidx];
        const float r2 = RAW[(size_t)(576 + 2 * 48 + pidx) * NTOK + t] + bqp[2 * 48 + pidx];
        #pragma unroll
        for (int x = 0; x < 3; x++) {
            const float v = R[x*3+0]*r0 + R[x*3+1]*r1 + R[x*3+2]*r2 + T3[x];
            QP[t * 144 + pidx * 3 + x] = v;
            AP[(size_t)(h * 28 + 16 + p * 3 + x) * NTOK + t] = hwS[h] * v;
        }
    }
    // kv points: pidx = h*12+pp; pp<4 -> BP (kp), else -> VPT
    for (int pidx = wk; pidx < 144; pidx += 16) {
        const int h = pidx / 12, pp = pidx % 12;
        const float r0 = RAW[(size_t)(720 + 0 * 144 + pidx) * NTOK + t] + bkvp[0 * 144 + pidx];
        const float r1 = RAW[(size_t)(720 + 1 * 144 + pidx) * NTOK + t] + bkvp[1 * 144 + pidx];
        const float r2 = RAW[(size_t)(720 + 2 * 144 + pidx) * NTOK + t] + bkvp[2 * 144 + pidx];
        #pragma unroll
        for (int x = 0; x < 3; x++) {
            const float v = R[x*3+0]*r0 + R[x*3+1]*r1 + R[x*3+2]*r2 + T3[x];
            if (pp < 4) BP[(size_t)(h * 28 + 16 + pp * 3 + x) * NTOK + t] = v;
            else        VPT[((h * 8 + pp - 4) * 3 + x) * NTOK + t] = v;
        }
    }
    __syncthreads();
    // norms (per head, per token)
    if (wk < NH) {
        const int h = wk;
        float sq = 0.f, sk = 0.f;
        #pragma unroll
        for (int d = 0; d < 12; d++) {
            const float a = QP[t * 144 + h * 12 + d];
            sq += a * a;
            const float b = BP[(size_t)(h * 28 + 16 + d) * NTOK + t];
            sk += b * b;
        }
        RQN[h * NTOK + t] = -0.5f * hwS[h] * sq;
        CKN[h * NTOK + t] = -0.5f * hwS[h] * sk;
    }
}

// ---------------------------------------------------------------------------
// K2: z projection, register-blocked GEMM, ONE i-row per block.
// R14 lesson: og*11 unaligned weight groups -> 11x ds_read_b32 (LDS-pipe
// bound). R16 lesson: 2-row variant (58.8KB LDS, 148 VGPR) -> 1 block/CU,
// 10% occupancy, 213us. This version: 48-pad alignment (3x ds_read_b128
// weights) + single row: LDS 41.7KB -> 3 blocks/CU, ~90 VGPR.
// ---------------------------------------------------------------------------
__global__ __launch_bounds__(256) void k2_zproj(
    const float* __restrict__ z, const float* __restrict__ wb, const float* __restrict__ bb,
    const float* __restrict__ wdz, const float* __restrict__ bdz,
    float* __restrict__ BBT, uint32* __restrict__ PZB)
{
    __shared__ float wL[CZ * 48];          // [k][48]: o<12 wb | o<44 wdz | pad
    __shared__ float zs[16][268];          // [kk][j-local], 16B-aligned rows
    const int tid = threadIdx.x;
    const int i  = blockIdx.y;
    const int j0 = blockIdx.x * 256;

    for (int idx = tid; idx < CZ * 48; idx += 256) {
        const int k = idx / 48, o = idx % 48;
        wL[idx] = (o < 12) ? wb[k * 12 + o] : ((o < 44) ? wdz[k * 32 + (o - 12)] : 0.f);
    }

    const int jq = tid & 63;               // j-quad
    const int og = tid >> 6;               // output group (wave-uniform), o = og*12+oo
    const int r0 = tid >> 2, c4 = tid & 3; // loader coords
    const float* zbase = z + ((size_t)i * NTOK + j0) * CZ;

    float4 acc[12];
    #pragma unroll
    for (int oo = 0; oo < 12; oo++) {
        const int o = og * 12 + oo;
        const float b = (o < 12) ? bb[o] : ((o < 44) ? bdz[o - 12] : 0.f);
        acc[oo] = make_float4(b, b, b, b);
    }

    float4 pre[4];
    #pragma unroll
    for (int w = 0; w < 4; w++)
        pre[w] = *(const float4*)&zbase[(size_t)(r0 + 64 * w) * CZ + c4 * 4];

    __syncthreads();                       // wL ready

    for (int kb = 0; kb < 8; kb++) {
        #pragma unroll
        for (int w = 0; w < 4; w++) {
            zs[c4 * 4 + 0][r0 + 64 * w] = pre[w].x;
            zs[c4 * 4 + 1][r0 + 64 * w] = pre[w].y;
            zs[c4 * 4 + 2][r0 + 64 * w] = pre[w].z;
            zs[c4 * 4 + 3][r0 + 64 * w] = pre[w].w;
        }
        __syncthreads();
        if (kb < 7) {
            #pragma unroll
            for (int w = 0; w < 4; w++)
                pre[w] = *(const float4*)&zbase[(size_t)(r0 + 64 * w) * CZ + (kb + 1) * 16 + c4 * 4];
        }
        #pragma unroll
        for (int kk = 0; kk < 16; kk++) {
            const float4 zv = *(const float4*)&zs[kk][jq * 4];
            const float* wrow = &wL[(kb * 16 + kk) * 48 + og * 12];   // 48B-aligned
            #pragma unroll
            for (int oo = 0; oo < 12; oo++) {
                const float w = wrow[oo];
                acc[oo].x += zv.x * w; acc[oo].y += zv.y * w;
                acc[oo].z += zv.z * w; acc[oo].w += zv.w * w;
            }
        }
        __syncthreads();
    }

    // PZ outputs (12 <= o < 44): bf16 pairs of adjacent j, coalesced uint2
    #pragma unroll
    for (int oo = 0; oo < 12; oo++) {
        const int o = og * 12 + oo;
        if (o >= 12 && o < 44) {
            const int c = o - 12;
            uint2 pk;
            pk.x = bf16rn(acc[oo].x) | (bf16rn(acc[oo].y) << 16);
            pk.y = bf16rn(acc[oo].z) | (bf16rn(acc[oo].w) << 16);
            *((uint2*)PZB + (size_t)(i * 32 + c) * 192 + (j0 >> 2) + jq) = pk;
        }
    }
    // BBT (o < 12, owned by og==0): transpose via zs (dead now), coalesced out
    if (og == 0) {
        #pragma unroll
        for (int oo = 0; oo < 12; oo++) {
            zs[oo][jq * 4 + 0] = acc[oo].x;
            zs[oo][jq * 4 + 1] = acc[oo].y;
            zs[oo][jq * 4 + 2] = acc[oo].z;
            zs[oo][jq * 4 + 3] = acc[oo].w;
        }
    }
    __syncthreads();
    for (int idx = tid; idx < 12 * 64; idx += 256) {
        const int o = idx >> 6, jl = idx & 63;
        *(float4*)&BBT[((size_t)i * 12 + o) * NTOK + j0 + jl * 4] =
            *(const float4*)&zs[o][jl * 4];
    }
}

// ---------------------------------------------------------------------------
// K3a: logit GEMM per head. LG[i][h][j] = AP_h[i].BP_h[j] + b_scale*BBT
//      + RQN[h][i] + CKN[h][j] + INF*(m_i*m_j - 1).  64x64 tiles, K=28.
// ---------------------------------------------------------------------------
__global__ __launch_bounds__(256) void k3a_logits(
    const float* __restrict__ AP, const float* __restrict__ BP,
    const float* __restrict__ RQN, const float* __restrict__ CKN,
    const float* __restrict__ BBT, const float* __restrict__ mask,
    float* __restrict__ LG)
{
    __shared__ float sA[28][64];
    __shared__ float sB[28][64];
    const int tid = threadIdx.x;
    const int j0 = blockIdx.x * 64;
    const int i0 = blockIdx.y * 64;
    const int h  = blockIdx.z;

    #pragma unroll
    for (int t = 0; t < 7; t++) {
        const int idx = tid + t * 256;
        const int row = idx >> 6, col = idx & 63;
        sA[row][col] = AP[(size_t)(h * 28 + row) * NTOK + i0 + col];
        sB[row][col] = BP[(size_t)(h * 28 + row) * NTOK + j0 + col];
    }
    __syncthreads();

    const int m0 = (tid & 15) * 4;   // i offset
    const int n0 = (tid >> 4) * 4;   // j offset

    float4 acc[4];   // acc[mm] = float4 over j
    #pragma unroll
    for (int mm = 0; mm < 4; mm++) acc[mm] = make_float4(0.f, 0.f, 0.f, 0.f);

    #pragma unroll
    for (int k = 0; k < 28; k++) {
        const float4 av = *(const float4*)&sA[k][m0];
        const float4 bv = *(const float4*)&sB[k][n0];
        acc[0].x += av.x * bv.x; acc[0].y += av.x * bv.y; acc[0].z += av.x * bv.z; acc[0].w += av.x * bv.w;
        acc[1].x += av.y * bv.x; acc[1].y += av.y * bv.y; acc[1].z += av.y * bv.z; acc[1].w += av.y * bv.w;
        acc[2].x += av.z * bv.x; acc[2].y += av.z * bv.y; acc[2].z += av.z * bv.z; acc[2].w += av.z * bv.w;
        acc[3].x += av.w * bv.x; acc[3].y += av.w * bv.y; acc[3].z += av.w * bv.z; acc[3].w += av.w * bv.w;
    }

    const float4 ck = *(const float4*)&CKN[h * NTOK + j0 + n0];
    const float4 mj = *(const float4*)&mask[j0 + n0];
    #pragma unroll
    for (int mm = 0; mm < 4; mm++) {
        const int gi = i0 + m0 + mm;
        const float rq = RQN[h * NTOK + gi];
        const float mi = mask[gi];
        const float4 bb = *(const float4*)&BBT[((size_t)gi * NH + h) * NTOK + j0 + n0];
        float4 o;
        o.x = acc[mm].x + B_SCALE * bb.x + rq + ck.x + INF_ * (mi * mj.x - 1.0f);
        o.y = acc[mm].y + B_SCALE * bb.y + rq + ck.y + INF_ * (mi * mj.y - 1.0f);
        o.z = acc[mm].z + B_SCALE * bb.z + rq + ck.z + INF_ * (mi * mj.z - 1.0f);
        o.w = acc[mm].w + B_SCALE * bb.w + rq + ck.w + INF_ * (mi * mj.w - 1.0f);
        *(float4*)&LG[((size_t)gi * NH + h) * NTOK + j0 + n0] = o;
    }
}

// ---------------------------------------------------------------------------
// K3b: per row i — load logits, softmax (wave=head), wave-cooperative sums.
// ---------------------------------------------------------------------------
__global__ __launch_bounds__(768) void k3b_attn(
    const float* __restrict__ LG,
    const float* __restrict__ VT, const float* __restrict__ VPT,
    const uint32* __restrict__ PZB,
    float* __restrict__ O, float* __restrict__ OPT, float* __restrict__ OPAIR)
{
    __shared__ float LB[NH][NTOK];      // logits -> probs in place
    const int i = blockIdx.x, tid = threadIdx.x;

    #pragma unroll
    for (int hh = 0; hh < NH; hh++)
        LB[hh][tid] = LG[((size_t)i * NH + hh) * NTOK + tid];
    __syncthreads();

    const int h = tid >> 6, l = tid & 63;   // wave w = head w (12 waves exactly)

    // softmax
    {
        float m = -3.0e38f;
        for (int jj = l; jj < NTOK; jj += 64) m = fmaxf(m, LB[h][jj]);
        #pragma unroll
        for (int off = 32; off >= 1; off >>= 1) m = fmaxf(m, __shfl_xor(m, off));
        float ssum = 0.0f;
        for (int jj = l; jj < NTOK; jj += 64) {
            const float e = __expf(LB[h][jj] - m);
            LB[h][jj] = e;
            ssum += e;
        }
        #pragma unroll
        for (int off = 32; off >= 1; off >>= 1) ssum += __shfl_xor(ssum, off);
        const float inv = 1.0f / ssum;
        for (int jj = l; jj < NTOK; jj += 64) LB[h][jj] *= inv;
    }
    __syncthreads();

    // wave-cooperative weighted sums (all loads coalesced)
    #pragma unroll 1
    for (int r = 0; r < 40; r++) {
        const float4* src = (r < 16) ? (const float4*)&VT[(h * 16 + r) * NTOK]
                                     : (const float4*)&VPT[(h * 24 + (r - 16)) * NTOK];
        const float4 v0 = src[l],       p0 = *(const float4*)&LB[h][l * 4];
        const float4 v1 = src[64 + l],  p1 = *(const float4*)&LB[h][256 + l * 4];
        const float4 v2 = src[128 + l], p2 = *(const float4*)&LB[h][512 + l * 4];
        float acc = p0.x*v0.x + p0.y*v0.y + p0.z*v0.z + p0.w*v0.w
                  + p1.x*v1.x + p1.y*v1.y + p1.z*v1.z + p1.w*v1.w
                  + p2.x*v2.x + p2.y*v2.y + p2.z*v2.z + p2.w*v2.w;
        #pragma unroll
        for (int off = 32; off >= 1; off >>= 1) acc += __shfl_xor(acc, off);
        if (l == 0) {
            if (r < 16) O[i * 192 + h * 16 + r] = acc;
            else        OPT[i * 288 + h * 24 + (r - 16)] = acc;
        }
    }
    // o_pair: 32 bf16 rows of PZB[i][c][j] (pairs of adjacent j per u32)
    #pragma unroll 1
    for (int c = 0; c < 32; c++) {
        const uint2* src = (const uint2*)PZB + (size_t)(i * 32 + c) * 192;
        float a = 0.f;
        #pragma unroll
        for (int it = 0; it < 3; it++) {
            const uint2 u = src[it * 64 + l];
            const float4 p = *(const float4*)&LB[h][it * 256 + l * 4];
            a += p.x * bflo(u.x) + p.y * bfhi(u.x)
               + p.z * bflo(u.y) + p.w * bfhi(u.y);
        }
        #pragma unroll
        for (int off = 32; off >= 1; off >>= 1) a += __shfl_xor(a, off);
        if (l == 0) OPAIR[i * 384 + h * 32 + c] = a;
    }
}

// ---------------------------------------------------------------------------
// K4: inverse rotation + norms + concat + final linear (8 tokens/block)
// ---------------------------------------------------------------------------
#define K4T 8
__global__ __launch_bounds__(256) void k4_out(
    const float* __restrict__ O, const float* __restrict__ OPT, const float* __restrict__ OPAIR,
    const float* __restrict__ rot, const float* __restrict__ trans,
    const float* __restrict__ wout, const float* __restrict__ bout,
    float* __restrict__ out)
{
    __shared__ float f[K4T][960];
    const int n0 = blockIdx.x * K4T, tid = threadIdx.x;

    for (int idx = tid; idx < K4T * 192; idx += 256) {
        const int t = idx / 192, k = idx % 192;
        f[t][k] = O[(n0 + t) * 192 + k];
    }
    for (int idx = tid; idx < K4T * 384; idx += 256) {
        const int t = idx / 384, k = idx % 384;
        f[t][576 + k] = OPAIR[(n0 + t) * 384 + k];
    }
    for (int idx = tid; idx < K4T * 96; idx += 256) {
        const int t = idx / 96, hp = idx % 96;
        const int n = n0 + t;
        const float vx = OPT[n * 288 + hp * 3 + 0] - trans[n * 3 + 0];
        const float vy = OPT[n * 288 + hp * 3 + 1] - trans[n * 3 + 1];
        const float vz = OPT[n * 288 + hp * 3 + 2] - trans[n * 3 + 2];
        const float o0 = rot[n*9+0]*vx + rot[n*9+3]*vy + rot[n*9+6]*vz;
        const float o1 = rot[n*9+1]*vx + rot[n*9+4]*vy + rot[n*9+7]*vz;
        const float o2 = rot[n*9+2]*vx + rot[n*9+5]*vy + rot[n*9+8]*vz;
        f[t][192 + hp] = o0;
        f[t][288 + hp] = o1;
        f[t][384 + hp] = o2;
        f[t][480 + hp] = sqrtf(o0*o0 + o1*o1 + o2*o2 + EPS_);
    }
    __syncthreads();

    for (int o = tid; o < 384; o += 256) {
        float acc[K4T];
        #pragma unroll
        for (int t = 0; t < K4T; t++) acc[t] = bout[o];
        for (int k = 0; k < 960; k++) {
            const float wv = wout[k * 384 + o];
            #pragma unroll
            for (int t = 0; t < K4T; t++) acc[t] += f[t][k] * wv;
        }
        #pragma unroll
        for (int t = 0; t < K4T; t++) out[(n0 + t) * 384 + o] = acc[t];
    }
}

// ---------------------------------------------------------------------------
extern "C" void kernel_launch(void* const* d_in, const int* in_sizes, int n_in,
                              void* d_out, int out_size, void* d_ws, size_t ws_size,
                              hipStream_t stream) {
    (void)in_sizes; (void)n_in; (void)out_size; (void)ws_size;
    const float* s     = (const float*)d_in[0];
    const float* z     = (const float*)d_in[1];
    const float* rot   = (const float*)d_in[2];
    const float* trans = (const float*)d_in[3];
    const float* mask  = (const float*)d_in[4];
    const float* wq    = (const float*)d_in[5];
    const float* bq    = (const float*)d_in[6];
    const float* wkv   = (const float*)d_in[7];
    const float* bkv   = (const float*)d_in[8];
    const float* wqp   = (const float*)d_in[9];
    const float* bqp   = (const float*)d_in[10];
    const float* wkvp  = (const float*)d_in[11];
    const float* bkvp  = (const float*)d_in[12];
    const float* wb    = (const float*)d_in[13];
    const float* bb    = (const float*)d_in[14];
    const float* wdz   = (const float*)d_in[15];
    const float* bdz   = (const float*)d_in[16];
    const float* hwts  = (const float*)d_in[17];
    const float* wout  = (const float*)d_in[18];
    const float* bout  = (const float*)d_in[19];
    float* out = (float*)d_out;

    float* ws = (float*)d_ws;
    float* Q     = ws;                       // 147456 (unused, kept for layout)
    float* KT    = Q     + 147456;           // 147456 (unused)
    float* VT    = KT    + 147456;           // 147456
    float* QP    = VT    + 147456;           // 110592
    float* KPT   = QP    + 110592;           // 110592 (unused)
    float* VPT   = KPT   + 110592;           // 221184
    float* O     = VPT   + 221184;           // 147456
    float* OPT   = O     + 147456;           // 221184
    float* OPAIR = OPT   + 221184;           // 294912
    float* BBT   = OPAIR + 294912;           // 7,077,888 floats (28.3 MB)
    uint32* PZB  = (uint32*)(BBT + 7077888); // 768*32*384 u32 (37.7 MB)
    float* AP    = BBT + 7077888 + 9437184;  // 12*28*768 = 258048
    float* BP    = AP  + 258048;             // 258048
    float* RQN   = BP  + 258048;             // 9216
    float* CKN   = RQN + 9216;               // 9216
    float* LG    = CKN + 9216;               // 7,077,888 floats (28.3 MB)
    float* RAW = BBT;   // aliases BBT: dead before k2 runs

    hipLaunchKernelGGL(k1a_gemm, dim3(NTOK / 64, 1152 / 64), dim3(256), 0, stream,
                       s, wq, wkv, wqp, wkvp, RAW);
    hipLaunchKernelGGL(k1b_finish, dim3(NTOK / 16), dim3(256), 0, stream,
                       RAW, rot, trans, bq, bkv, bqp, bkvp, hwts,
                       VT, QP, VPT, AP, BP, RQN, CKN);
    hipLaunchKernelGGL(k2_zproj, dim3(3, NTOK), dim3(256), 0, stream,
                       z, wb, bb, wdz, bdz, BBT, PZB);
    hipLaunchKernelGGL(k3a_logits, dim3(NTOK / 64, NTOK / 64, NH), dim3(256), 0, stream,
                       AP, BP, RQN, CKN, BBT, mask, LG);
    hipLaunchKernelGGL(k3b_attn, dim3(NTOK), dim3(768), 0, stream,
                       LG, VT, VPT, PZB, O, OPT, OPAIR);
    hipLaunchKernelGGL(k4_out, dim3(NTOK / K4T), dim3(256), 0, stream,
                       O, OPT, OPAIR, rot, trans, wout, bout, out);
}

// Round 18
// 468.012 us; speedup vs baseline: 1.1133x; 1.0001x over previous
//
#include <hip/hip_runtime.h>
#include <math.h>

#define NTOK 768
#define CS   384
#define CZ   128
#define NH   12
#define INF_ 100000.0f
#define EPS_ 1e-8f

typedef unsigned int  uint32;
typedef __attribute__((ext_vector_type(8))) short bf16x8;
typedef __attribute__((ext_vector_type(4))) float f32x4;

__device__ __forceinline__ uint32 bf16rn(float x) {
    uint32 u = __float_as_uint(x);
    return (u + 0x7fffu + ((u >> 16) & 1u)) >> 16;
}
__device__ __forceinline__ float bflo(uint32 u) { return __uint_as_float((u & 0xffffu) << 16); }
__device__ __forceinline__ float bfhi(uint32 u) { return __uint_as_float(u & 0xffff0000u); }

#define QK_SCALE 0.14433756729740643f   // sqrt(1/48)
#define B_SCALE  0.5773502691896258f    // sqrt(1/3)
#define HW_SCALE 0.13608276348795434f   // sqrt(1/54)

// ---------------------------------------------------------------------------
// K1a: tiled GEMM. RAW[col][tok] = sum_k s[tok][k] * Wcat[k][col]  (no bias).
// ---------------------------------------------------------------------------
__global__ __launch_bounds__(256) void k1a_gemm(
    const float* __restrict__ s,
    const float* __restrict__ wq, const float* __restrict__ wkv,
    const float* __restrict__ wqp, const float* __restrict__ wkvp,
    float* __restrict__ RAW)
{
    __shared__ float sA[32][72];   // [k][m]
    __shared__ float sB[32][72];   // [k][n]
    const int tid  = threadIdx.x;
    const int tok0 = blockIdx.x * 64;
    const int col0 = blockIdx.y * 64;

    const int m0 = (tid & 15) * 4;
    const int n0 = (tid >> 4) * 4;

    float4 acc[4];
    #pragma unroll
    for (int nn = 0; nn < 4; nn++) acc[nn] = make_float4(0.f, 0.f, 0.f, 0.f);

    const int lam = tid >> 2, lak = (tid & 3) * 8;
    const int lbk = tid >> 3, lbc = (tid & 7) * 8;
    const int gcol = col0 + lbc;
    const float* wsrc; int wwidth, woff;
    if (gcol < 192)      { wsrc = wq;   wwidth = 192; woff = gcol; }
    else if (gcol < 576) { wsrc = wkv;  wwidth = 384; woff = gcol - 192; }
    else if (gcol < 720) { wsrc = wqp;  wwidth = 144; woff = gcol - 576; }
    else                 { wsrc = wkvp; wwidth = 432; woff = gcol - 720; }

    for (int kb = 0; kb < CS; kb += 32) {
        const float4 a0 = *(const float4*)&s[(tok0 + lam) * CS + kb + lak];
        const float4 a1 = *(const float4*)&s[(tok0 + lam) * CS + kb + lak + 4];
        const float4 b0 = *(const float4*)&wsrc[(size_t)(kb + lbk) * wwidth + woff];
        const float4 b1 = *(const float4*)&wsrc[(size_t)(kb + lbk) * wwidth + woff + 4];
        __syncthreads();
        sA[lak + 0][lam] = a0.x; sA[lak + 1][lam] = a0.y;
        sA[lak + 2][lam] = a0.z; sA[lak + 3][lam] = a0.w;
        sA[lak + 4][lam] = a1.x; sA[lak + 5][lam] = a1.y;
        sA[lak + 6][lam] = a1.z; sA[lak + 7][lam] = a1.w;
        *(float4*)&sB[lbk][lbc]     = b0;
        *(float4*)&sB[lbk][lbc + 4] = b1;
        __syncthreads();
        #pragma unroll
        for (int k = 0; k < 32; k++) {
            const float4 av = *(const float4*)&sA[k][m0];
            const float4 bv = *(const float4*)&sB[k][n0];
            acc[0].x += av.x * bv.x; acc[0].y += av.y * bv.x; acc[0].z += av.z * bv.x; acc[0].w += av.w * bv.x;
            acc[1].x += av.x * bv.y; acc[1].y += av.y * bv.y; acc[1].z += av.z * bv.y; acc[1].w += av.w * bv.y;
            acc[2].x += av.x * bv.z; acc[2].y += av.y * bv.z; acc[2].z += av.z * bv.z; acc[2].w += av.w * bv.z;
            acc[3].x += av.x * bv.w; acc[3].y += av.y * bv.w; acc[3].z += av.z * bv.w; acc[3].w += av.w * bv.w;
        }
    }
    #pragma unroll
    for (int nn = 0; nn < 4; nn++)
        *(float4*)&RAW[(size_t)(col0 + n0 + nn) * NTOK + tok0 + m0] = acc[nn];
}

// ---------------------------------------------------------------------------
// K1b: bias + rigid transform + GEMM-operand packing for the logit GEMM.
// ---------------------------------------------------------------------------
__global__ __launch_bounds__(256) void k1b_finish(
    const float* __restrict__ RAW,
    const float* __restrict__ rot, const float* __restrict__ trans,
    const float* __restrict__ bq, const float* __restrict__ bkv,
    const float* __restrict__ bqp, const float* __restrict__ bkvp,
    const float* __restrict__ head_weights,
    float* __restrict__ VT, float* __restrict__ QP, float* __restrict__ VPT,
    float* __restrict__ AP, float* __restrict__ BP,
    float* __restrict__ RQN, float* __restrict__ CKN)
{
    __shared__ float hwS[NH];
    const int tid = threadIdx.x;
    const int t  = blockIdx.x * 16 + (tid & 15);
    const int wk = tid >> 4;                      // 16 walkers

    if (tid < NH) hwS[tid] = logf(1.0f + expf(head_weights[tid])) * HW_SCALE;

    float R[9], T3[3];
    #pragma unroll
    for (int x = 0; x < 9; x++) R[x] = rot[t * 9 + x];
    #pragma unroll
    for (int x = 0; x < 3; x++) T3[x] = trans[t * 3 + x];
    __syncthreads();

    // q -> AP (scaled)
    for (int col = wk; col < 192; col += 16) {
        const int h = col >> 4, c = col & 15;
        AP[(size_t)(h * 28 + c) * NTOK + t] = QK_SCALE * (RAW[(size_t)col * NTOK + t] + bq[col]);
    }
    // k -> BP, v -> VT
    for (int idx = wk; idx < 192; idx += 16) {
        const int h = idx >> 4, c = idx & 15;
        BP[(size_t)(h * 28 + c) * NTOK + t] = RAW[(size_t)(192 + h * 32 + c) * NTOK + t] + bkv[h * 32 + c];
        VT[idx * NTOK + t] = RAW[(size_t)(192 + h * 32 + 16 + c) * NTOK + t] + bkv[h * 32 + 16 + c];
    }
    // q points: pidx = h*4+p -> QP + AP (hw-scaled)
    for (int pidx = wk; pidx < 48; pidx += 16) {
        const int h = pidx >> 2, p = pidx & 3;
        const float r0 = RAW[(size_t)(576 + 0 * 48 + pidx) * NTOK + t] + bqp[0 * 48 + pidx];
        const float r1 = RAW[(size_t)(576 + 1 * 48 + pidx) * NTOK + t] + bqp[1 * 48 + pidx];
        const float r2 = RAW[(size_t)(576 + 2 * 48 + pidx) * NTOK + t] + bqp[2 * 48 + pidx];
        #pragma unroll
        for (int x = 0; x < 3; x++) {
            const float v = R[x*3+0]*r0 + R[x*3+1]*r1 + R[x*3+2]*r2 + T3[x];
            QP[t * 144 + pidx * 3 + x] = v;
            AP[(size_t)(h * 28 + 16 + p * 3 + x) * NTOK + t] = hwS[h] * v;
        }
    }
    // kv points: pidx = h*12+pp; pp<4 -> BP (kp), else -> VPT
    for (int pidx = wk; pidx < 144; pidx += 16) {
        const int h = pidx / 12, pp = pidx % 12;
        const float r0 = RAW[(size_t)(720 + 0 * 144 + pidx) * NTOK + t] + bkvp[0 * 144 + pidx];
        const float r1 = RAW[(size_t)(720 + 1 * 144 + pidx) * NTOK + t] + bkvp[1 * 144 + pidx];
        const float r2 = RAW[(size_t)(720 + 2 * 144 + pidx) * NTOK + t] + bkvp[2 * 144 + pidx];
        #pragma unroll
        for (int x = 0; x < 3; x++) {
            const float v = R[x*3+0]*r0 + R[x*3+1]*r1 + R[x*3+2]*r2 + T3[x];
            if (pp < 4) BP[(size_t)(h * 28 + 16 + pp * 3 + x) * NTOK + t] = v;
            else        VPT[((h * 8 + pp - 4) * 3 + x) * NTOK + t] = v;
        }
    }
    __syncthreads();
    // norms (per head, per token)
    if (wk < NH) {
        const int h = wk;
        float sq = 0.f, sk = 0.f;
        #pragma unroll
        for (int d = 0; d < 12; d++) {
            const float a = QP[t * 144 + h * 12 + d];
            sq += a * a;
            const float b = BP[(size_t)(h * 28 + 16 + d) * NTOK + t];
            sk += b * b;
        }
        RQN[h * NTOK + t] = -0.5f * hwS[h] * sq;
        CKN[h * NTOK + t] = -0.5f * hwS[h] * sk;
    }
}

// ---------------------------------------------------------------------------
// K2 (MFMA): z-projection GEMM via mfma_f32_16x16x32_bf16.
// R17 postmortem: any f32 VALU formulation is LDS-issue-bound (4 b128 reads
// per 48 FMAs -> 92us LDS floor). MFMA: 512 MACs per instr; B frags (weights,
// bf16, [o][k] in LDS, 12 reads/wave total), A (z) straight from global with
// f32->bf16 pack. Block = 4 waves, each wave one 16-j tile; 64 j x 48 o per
// block; grid = 768 i * 12 j-tiles = 9216.
// C/D layout (m89-verified): col = lane&15 (=o), row = (lane>>4)*4+reg (=j).
// A/B fed with identical k-mapping -> k-order errors cancel.
// ---------------------------------------------------------------------------
__global__ __launch_bounds__(256) void k2_zproj_mfma(
    const float* __restrict__ z, const float* __restrict__ wb, const float* __restrict__ bb,
    const float* __restrict__ wdz, const float* __restrict__ bdz,
    float* __restrict__ BBT, uint32* __restrict__ PZB)
{
    __shared__ __align__(16) unsigned short wB[48 * 136];  // [o][k] bf16, 272B rows
    __shared__ float outS[64][52];                         // [j-local][o] + pad
    __shared__ float bbS[12], bdzS[32];

    const int tid = threadIdx.x;
    const int i   = blockIdx.x / 12;
    const int j0  = (blockIdx.x % 12) * 64;
    const int l   = tid & 63;
    const int jt  = tid >> 6;            // wave id = 16-j sub-tile

    // stage weights as bf16, k-contiguous rows
    for (int idx = tid; idx < 48 * 64; idx += 256) {
        const int o = idx >> 6, k2 = (idx & 63) * 2;
        float f0, f1;
        if (o < 12)      { f0 = wb[k2 * 12 + o];         f1 = wb[(k2 + 1) * 12 + o]; }
        else if (o < 44) { f0 = wdz[k2 * 32 + (o - 12)]; f1 = wdz[(k2 + 1) * 32 + (o - 12)]; }
        else             { f0 = 0.f; f1 = 0.f; }
        *(uint32*)&wB[o * 136 + k2] = bf16rn(f0) | (bf16rn(f1) << 16);
    }
    if (tid < 12) bbS[tid] = bb[tid];
    else if (tid >= 32 && tid < 64) bdzS[tid - 32] = bdz[tid - 32];
    __syncthreads();

    // B fragments: [o-tile][k-step]; lane: col = l&15, k = ks*32 + (l>>4)*8
    bf16x8 Bf[3][4];
    #pragma unroll
    for (int t = 0; t < 3; t++)
        #pragma unroll
        for (int ks = 0; ks < 4; ks++)
            Bf[t][ks] = *(const bf16x8*)&wB[(t * 16 + (l & 15)) * 136 + ks * 32 + (l >> 4) * 8];

    // A source: row j = j0 + jt*16 + (l&15), k base (l>>4)*8
    const float* zrow = z + ((size_t)i * NTOK + j0 + jt * 16 + (l & 15)) * CZ + (l >> 4) * 8;

    f32x4 acc[3];
    #pragma unroll
    for (int t = 0; t < 3; t++) acc[t] = (f32x4){0.f, 0.f, 0.f, 0.f};

    #pragma unroll
    for (int ks = 0; ks < 4; ks++) {
        const float4 a0 = *(const float4*)&zrow[ks * 32];
        const float4 a1 = *(const float4*)&zrow[ks * 32 + 4];
        union { uint32 u[4]; bf16x8 v; } A;
        A.u[0] = bf16rn(a0.x) | (bf16rn(a0.y) << 16);
        A.u[1] = bf16rn(a0.z) | (bf16rn(a0.w) << 16);
        A.u[2] = bf16rn(a1.x) | (bf16rn(a1.y) << 16);
        A.u[3] = bf16rn(a1.z) | (bf16rn(a1.w) << 16);
        #pragma unroll
        for (int t = 0; t < 3; t++)
            acc[t] = __builtin_amdgcn_mfma_f32_16x16x32_bf16(A.v, Bf[t][ks], acc[t], 0, 0, 0);
    }

    // scatter D to LDS: lane l, reg v -> j_local = jt*16 + (l>>4)*4 + v, o = t*16 + (l&15)
    #pragma unroll
    for (int t = 0; t < 3; t++) {
        const int o = t * 16 + (l & 15);
        #pragma unroll
        for (int v = 0; v < 4; v++)
            outS[jt * 16 + (l >> 4) * 4 + v][o] = acc[t][v];
    }
    __syncthreads();

    // BBT[i][o][j] f32 (+bias), coalesced over j
    for (int idx = tid; idx < 12 * 64; idx += 256) {
        const int o = idx >> 6, jl = idx & 63;
        BBT[((size_t)i * 12 + o) * NTOK + j0 + jl] = outS[jl][o] + bbS[o];
    }
    // PZB[i][c][j-pair] bf16 (+bias), coalesced over j-pairs
    for (int idx = tid; idx < 32 * 32; idx += 256) {
        const int c = idx >> 5, jp = idx & 31;
        const float f0 = outS[jp * 2][12 + c] + bdzS[c];
        const float f1 = outS[jp * 2 + 1][12 + c] + bdzS[c];
        PZB[(size_t)(i * 32 + c) * 384 + (j0 >> 1) + jp] = bf16rn(f0) | (bf16rn(f1) << 16);
    }
}

// ---------------------------------------------------------------------------
// K3a: logit GEMM per head. LG[i][h][j] = AP_h[i].BP_h[j] + b_scale*BBT
//      + RQN[h][i] + CKN[h][j] + INF*(m_i*m_j - 1).  64x64 tiles, K=28.
// ---------------------------------------------------------------------------
__global__ __launch_bounds__(256) void k3a_logits(
    const float* __restrict__ AP, const float* __restrict__ BP,
    const float* __restrict__ RQN, const float* __restrict__ CKN,
    const float* __restrict__ BBT, const float* __restrict__ mask,
    float* __restrict__ LG)
{
    __shared__ float sA[28][64];
    __shared__ float sB[28][64];
    const int tid = threadIdx.x;
    const int j0 = blockIdx.x * 64;
    const int i0 = blockIdx.y * 64;
    const int h  = blockIdx.z;

    #pragma unroll
    for (int t = 0; t < 7; t++) {
        const int idx = tid + t * 256;
        const int row = idx >> 6, col = idx & 63;
        sA[row][col] = AP[(size_t)(h * 28 + row) * NTOK + i0 + col];
        sB[row][col] = BP[(size_t)(h * 28 + row) * NTOK + j0 + col];
    }
    __syncthreads();

    const int m0 = (tid & 15) * 4;   // i offset
    const int n0 = (tid >> 4) * 4;   // j offset

    float4 acc[4];   // acc[mm] = float4 over j
    #pragma unroll
    for (int mm = 0; mm < 4; mm++) acc[mm] = make_float4(0.f, 0.f, 0.f, 0.f);

    #pragma unroll
    for (int k = 0; k < 28; k++) {
        const float4 av = *(const float4*)&sA[k][m0];
        const float4 bv = *(const float4*)&sB[k][n0];
        acc[0].x += av.x * bv.x; acc[0].y += av.x * bv.y; acc[0].z += av.x * bv.z; acc[0].w += av.x * bv.w;
        acc[1].x += av.y * bv.x; acc[1].y += av.y * bv.y; acc[1].z += av.y * bv.z; acc[1].w += av.y * bv.w;
        acc[2].x += av.z * bv.x; acc[2].y += av.z * bv.y; acc[2].z += av.z * bv.z; acc[2].w += av.z * bv.w;
        acc[3].x += av.w * bv.x; acc[3].y += av.w * bv.y; acc[3].z += av.w * bv.z; acc[3].w += av.w * bv.w;
    }

    const float4 ck = *(const float4*)&CKN[h * NTOK + j0 + n0];
    const float4 mj = *(const float4*)&mask[j0 + n0];
    #pragma unroll
    for (int mm = 0; mm < 4; mm++) {
        const int gi = i0 + m0 + mm;
        const float rq = RQN[h * NTOK + gi];
        const float mi = mask[gi];
        const float4 bb = *(const float4*)&BBT[((size_t)gi * NH + h) * NTOK + j0 + n0];
        float4 o;
        o.x = acc[mm].x + B_SCALE * bb.x + rq + ck.x + INF_ * (mi * mj.x - 1.0f);
        o.y = acc[mm].y + B_SCALE * bb.y + rq + ck.y + INF_ * (mi * mj.y - 1.0f);
        o.z = acc[mm].z + B_SCALE * bb.z + rq + ck.z + INF_ * (mi * mj.z - 1.0f);
        o.w = acc[mm].w + B_SCALE * bb.w + rq + ck.w + INF_ * (mi * mj.w - 1.0f);
        *(float4*)&LG[((size_t)gi * NH + h) * NTOK + j0 + n0] = o;
    }
}

// ---------------------------------------------------------------------------
// K3b: per row i — load logits, softmax (wave=head), wave-cooperative sums.
// ---------------------------------------------------------------------------
__global__ __launch_bounds__(768) void k3b_attn(
    const float* __restrict__ LG,
    const float* __restrict__ VT, const float* __restrict__ VPT,
    const uint32* __restrict__ PZB,
    float* __restrict__ O, float* __restrict__ OPT, float* __restrict__ OPAIR)
{
    __shared__ float LB[NH][NTOK];      // logits -> probs in place
    const int i = blockIdx.x, tid = threadIdx.x;

    #pragma unroll
    for (int hh = 0; hh < NH; hh++)
        LB[hh][tid] = LG[((size_t)i * NH + hh) * NTOK + tid];
    __syncthreads();

    const int h = tid >> 6, l = tid & 63;   // wave w = head w (12 waves exactly)

    // softmax
    {
        float m = -3.0e38f;
        for (int jj = l; jj < NTOK; jj += 64) m = fmaxf(m, LB[h][jj]);
        #pragma unroll
        for (int off = 32; off >= 1; off >>= 1) m = fmaxf(m, __shfl_xor(m, off));
        float ssum = 0.0f;
        for (int jj = l; jj < NTOK; jj += 64) {
            const float e = __expf(LB[h][jj] - m);
            LB[h][jj] = e;
            ssum += e;
        }
        #pragma unroll
        for (int off = 32; off >= 1; off >>= 1) ssum += __shfl_xor(ssum, off);
        const float inv = 1.0f / ssum;
        for (int jj = l; jj < NTOK; jj += 64) LB[h][jj] *= inv;
    }
    __syncthreads();

    // wave-cooperative weighted sums (all loads coalesced)
    #pragma unroll 1
    for (int r = 0; r < 40; r++) {
        const float4* src = (r < 16) ? (const float4*)&VT[(h * 16 + r) * NTOK]
                                     : (const float4*)&VPT[(h * 24 + (r - 16)) * NTOK];
        const float4 v0 = src[l],       p0 = *(const float4*)&LB[h][l * 4];
        const float4 v1 = src[64 + l],  p1 = *(const float4*)&LB[h][256 + l * 4];
        const float4 v2 = src[128 + l], p2 = *(const float4*)&LB[h][512 + l * 4];
        float acc = p0.x*v0.x + p0.y*v0.y + p0.z*v0.z + p0.w*v0.w
                  + p1.x*v1.x + p1.y*v1.y + p1.z*v1.z + p1.w*v1.w
                  + p2.x*v2.x + p2.y*v2.y + p2.z*v2.z + p2.w*v2.w;
        #pragma unroll
        for (int off = 32; off >= 1; off >>= 1) acc += __shfl_xor(acc, off);
        if (l == 0) {
            if (r < 16) O[i * 192 + h * 16 + r] = acc;
            else        OPT[i * 288 + h * 24 + (r - 16)] = acc;
        }
    }
    // o_pair: 32 bf16 rows of PZB[i][c][j] (pairs of adjacent j per u32)
    #pragma unroll 1
    for (int c = 0; c < 32; c++) {
        const uint2* src = (const uint2*)PZB + (size_t)(i * 32 + c) * 192;
        float a = 0.f;
        #pragma unroll
        for (int it = 0; it < 3; it++) {
            const uint2 u = src[it * 64 + l];
            const float4 p = *(const float4*)&LB[h][it * 256 + l * 4];
            a += p.x * bflo(u.x) + p.y * bfhi(u.x)
               + p.z * bflo(u.y) + p.w * bfhi(u.y);
        }
        #pragma unroll
        for (int off = 32; off >= 1; off >>= 1) a += __shfl_xor(a, off);
        if (l == 0) OPAIR[i * 384 + h * 32 + c] = a;
    }
}

// ---------------------------------------------------------------------------
// K4: inverse rotation + norms + concat + final linear (8 tokens/block)
// ---------------------------------------------------------------------------
#define K4T 8
__global__ __launch_bounds__(256) void k4_out(
    const float* __restrict__ O, const float* __restrict__ OPT, const float* __restrict__ OPAIR,
    const float* __restrict__ rot, const float* __restrict__ trans,
    const float* __restrict__ wout, const float* __restrict__ bout,
    float* __restrict__ out)
{
    __shared__ float f[K4T][960];
    const int n0 = blockIdx.x * K4T, tid = threadIdx.x;

    for (int idx = tid; idx < K4T * 192; idx += 256) {
        const int t = idx / 192, k = idx % 192;
        f[t][k] = O[(n0 + t) * 192 + k];
    }
    for (int idx = tid; idx < K4T * 384; idx += 256) {
        const int t = idx / 384, k = idx % 384;
        f[t][576 + k] = OPAIR[(n0 + t) * 384 + k];
    }
    for (int idx = tid; idx < K4T * 96; idx += 256) {
        const int t = idx / 96, hp = idx % 96;
        const int n = n0 + t;
        const float vx = OPT[n * 288 + hp * 3 + 0] - trans[n * 3 + 0];
        const float vy = OPT[n * 288 + hp * 3 + 1] - trans[n * 3 + 1];
        const float vz = OPT[n * 288 + hp * 3 + 2] - trans[n * 3 + 2];
        const float o0 = rot[n*9+0]*vx + rot[n*9+3]*vy + rot[n*9+6]*vz;
        const float o1 = rot[n*9+1]*vx + rot[n*9+4]*vy + rot[n*9+7]*vz;
        const float o2 = rot[n*9+2]*vx + rot[n*9+5]*vy + rot[n*9+8]*vz;
        f[t][192 + hp] = o0;
        f[t][288 + hp] = o1;
        f[t][384 + hp] = o2;
        f[t][480 + hp] = sqrtf(o0*o0 + o1*o1 + o2*o2 + EPS_);
    }
    __syncthreads();

    for (int o = tid; o < 384; o += 256) {
        float acc[K4T];
        #pragma unroll
        for (int t = 0; t < K4T; t++) acc[t] = bout[o];
        for (int k = 0; k < 960; k++) {
            const float wv = wout[k * 384 + o];
            #pragma unroll
            for (int t = 0; t < K4T; t++) acc[t] += f[t][k] * wv;
        }
        #pragma unroll
        for (int t = 0; t < K4T; t++) out[(n0 + t) * 384 + o] = acc[t];
    }
}

// ---------------------------------------------------------------------------
extern "C" void kernel_launch(void* const* d_in, const int* in_sizes, int n_in,
                              void* d_out, int out_size, void* d_ws, size_t ws_size,
                              hipStream_t stream) {
    (void)in_sizes; (void)n_in; (void)out_size; (void)ws_size;
    const float* s     = (const float*)d_in[0];
    const float* z     = (const float*)d_in[1];
    const float* rot   = (const float*)d_in[2];
    const float* trans = (const float*)d_in[3];
    const float* mask  = (const float*)d_in[4];
    const float* wq    = (const float*)d_in[5];
    const float* bq    = (const float*)d_in[6];
    const float* wkv   = (const float*)d_in[7];
    const float* bkv   = (const float*)d_in[8];
    const float* wqp   = (const float*)d_in[9];
    const float* bqp   = (const float*)d_in[10];
    const float* wkvp  = (const float*)d_in[11];
    const float* bkvp  = (const float*)d_in[12];
    const float* wb    = (const float*)d_in[13];
    const float* bb    = (const float*)d_in[14];
    const float* wdz   = (const float*)d_in[15];
    const float* bdz   = (const float*)d_in[16];
    const float* hwts  = (const float*)d_in[17];
    const float* wout  = (const float*)d_in[18];
    const float* bout  = (const float*)d_in[19];
    float* out = (float*)d_out;

    float* ws = (float*)d_ws;
    float* Q     = ws;                       // 147456 (unused, kept for layout)
    float* KT    = Q     + 147456;           // 147456 (unused)
    float* VT    = KT    + 147456;           // 147456
    float* QP    = VT    + 147456;           // 110592
    float* KPT   = QP    + 110592;           // 110592 (unused)
    float* VPT   = KPT   + 110592;           // 221184
    float* O     = VPT   + 221184;           // 147456
    float* OPT   = O     + 147456;           // 221184
    float* OPAIR = OPT   + 221184;           // 294912
    float* BBT   = OPAIR + 294912;           // 7,077,888 floats (28.3 MB)
    uint32* PZB  = (uint32*)(BBT + 7077888); // 768*32*384 u32 (37.7 MB)
    float* AP    = BBT + 7077888 + 9437184;  // 12*28*768 = 258048
    float* BP    = AP  + 258048;             // 258048
    float* RQN   = BP  + 258048;             // 9216
    float* CKN   = RQN + 9216;               // 9216
    float* LG    = CKN + 9216;               // 7,077,888 floats (28.3 MB)
    float* RAW = BBT;   // aliases BBT: dead before k2 runs

    hipLaunchKernelGGL(k1a_gemm, dim3(NTOK / 64, 1152 / 64), dim3(256), 0, stream,
                       s, wq, wkv, wqp, wkvp, RAW);
    hipLaunchKernelGGL(k1b_finish, dim3(NTOK / 16), dim3(256), 0, stream,
                       RAW, rot, trans, bq, bkv, bqp, bkvp, hwts,
                       VT, QP, VPT, AP, BP, RQN, CKN);
    hipLaunchKernelGGL(k2_zproj_mfma, dim3(NTOK * 12), dim3(256), 0, stream,
                       z, wb, bb, wdz, bdz, BBT, PZB);
    hipLaunchKernelGGL(k3a_logits, dim3(NTOK / 64, NTOK / 64, NH), dim3(256), 0, stream,
                       AP, BP, RQN, CKN, BBT, mask, LG);
    hipLaunchKernelGGL(k3b_attn, dim3(NTOK), dim3(768), 0, stream,
                       LG, VT, VPT, PZB, O, OPT, OPAIR);
    hipLaunchKernelGGL(k4_out, dim3(NTOK / K4T), dim3(256), 0, stream,
                       O, OPT, OPAIR, rot, trans, wout, bout, out);
}

// Round 19
// 412.977 us; speedup vs baseline: 1.2617x; 1.1333x over previous
//
#include <hip/hip_runtime.h>
#include <math.h>

#define NTOK 768
#define CS   384
#define CZ   128
#define NH   12
#define INF_ 100000.0f
#define EPS_ 1e-8f

typedef unsigned int  uint32;
typedef __attribute__((ext_vector_type(8))) short bf16x8;
typedef __attribute__((ext_vector_type(4))) float f32x4;

__device__ __forceinline__ uint32 bf16rn(float x) {
    uint32 u = __float_as_uint(x);
    return (u + 0x7fffu + ((u >> 16) & 1u)) >> 16;
}
__device__ __forceinline__ float bflo(uint32 u) { return __uint_as_float((u & 0xffffu) << 16); }
__device__ __forceinline__ float bfhi(uint32 u) { return __uint_as_float(u & 0xffff0000u); }

#define QK_SCALE 0.14433756729740643f   // sqrt(1/48)
#define B_SCALE  0.5773502691896258f    // sqrt(1/3)
#define HW_SCALE 0.13608276348795434f   // sqrt(1/54)

// ---------------------------------------------------------------------------
// K1a: tiled GEMM. RAW[col][tok] = sum_k s[tok][k] * Wcat[k][col]  (no bias).
// ---------------------------------------------------------------------------
__global__ __launch_bounds__(256) void k1a_gemm(
    const float* __restrict__ s,
    const float* __restrict__ wq, const float* __restrict__ wkv,
    const float* __restrict__ wqp, const float* __restrict__ wkvp,
    float* __restrict__ RAW)
{
    __shared__ float sA[32][72];   // [k][m]
    __shared__ float sB[32][72];   // [k][n]
    const int tid  = threadIdx.x;
    const int tok0 = blockIdx.x * 64;
    const int col0 = blockIdx.y * 64;

    const int m0 = (tid & 15) * 4;
    const int n0 = (tid >> 4) * 4;

    float4 acc[4];
    #pragma unroll
    for (int nn = 0; nn < 4; nn++) acc[nn] = make_float4(0.f, 0.f, 0.f, 0.f);

    const int lam = tid >> 2, lak = (tid & 3) * 8;
    const int lbk = tid >> 3, lbc = (tid & 7) * 8;
    const int gcol = col0 + lbc;
    const float* wsrc; int wwidth, woff;
    if (gcol < 192)      { wsrc = wq;   wwidth = 192; woff = gcol; }
    else if (gcol < 576) { wsrc = wkv;  wwidth = 384; woff = gcol - 192; }
    else if (gcol < 720) { wsrc = wqp;  wwidth = 144; woff = gcol - 576; }
    else                 { wsrc = wkvp; wwidth = 432; woff = gcol - 720; }

    for (int kb = 0; kb < CS; kb += 32) {
        const float4 a0 = *(const float4*)&s[(tok0 + lam) * CS + kb + lak];
        const float4 a1 = *(const float4*)&s[(tok0 + lam) * CS + kb + lak + 4];
        const float4 b0 = *(const float4*)&wsrc[(size_t)(kb + lbk) * wwidth + woff];
        const float4 b1 = *(const float4*)&wsrc[(size_t)(kb + lbk) * wwidth + woff + 4];
        __syncthreads();
        sA[lak + 0][lam] = a0.x; sA[lak + 1][lam] = a0.y;
        sA[lak + 2][lam] = a0.z; sA[lak + 3][lam] = a0.w;
        sA[lak + 4][lam] = a1.x; sA[lak + 5][lam] = a1.y;
        sA[lak + 6][lam] = a1.z; sA[lak + 7][lam] = a1.w;
        *(float4*)&sB[lbk][lbc]     = b0;
        *(float4*)&sB[lbk][lbc + 4] = b1;
        __syncthreads();
        #pragma unroll
        for (int k = 0; k < 32; k++) {
            const float4 av = *(const float4*)&sA[k][m0];
            const float4 bv = *(const float4*)&sB[k][n0];
            acc[0].x += av.x * bv.x; acc[0].y += av.y * bv.x; acc[0].z += av.z * bv.x; acc[0].w += av.w * bv.x;
            acc[1].x += av.x * bv.y; acc[1].y += av.y * bv.y; acc[1].z += av.z * bv.y; acc[1].w += av.w * bv.y;
            acc[2].x += av.x * bv.z; acc[2].y += av.y * bv.z; acc[2].z += av.z * bv.z; acc[2].w += av.w * bv.z;
            acc[3].x += av.x * bv.w; acc[3].y += av.y * bv.w; acc[3].z += av.z * bv.w; acc[3].w += av.w * bv.w;
        }
    }
    #pragma unroll
    for (int nn = 0; nn < 4; nn++)
        *(float4*)&RAW[(size_t)(col0 + n0 + nn) * NTOK + tok0 + m0] = acc[nn];
}

// ---------------------------------------------------------------------------
// K1b: bias + rigid transform + GEMM-operand packing for the logit GEMM.
// ---------------------------------------------------------------------------
__global__ __launch_bounds__(256) void k1b_finish(
    const float* __restrict__ RAW,
    const float* __restrict__ rot, const float* __restrict__ trans,
    const float* __restrict__ bq, const float* __restrict__ bkv,
    const float* __restrict__ bqp, const float* __restrict__ bkvp,
    const float* __restrict__ head_weights,
    float* __restrict__ VT, float* __restrict__ QP, float* __restrict__ VPT,
    float* __restrict__ AP, float* __restrict__ BP,
    float* __restrict__ RQN, float* __restrict__ CKN)
{
    __shared__ float hwS[NH];
    const int tid = threadIdx.x;
    const int t  = blockIdx.x * 16 + (tid & 15);
    const int wk = tid >> 4;                      // 16 walkers

    if (tid < NH) hwS[tid] = logf(1.0f + expf(head_weights[tid])) * HW_SCALE;

    float R[9], T3[3];
    #pragma unroll
    for (int x = 0; x < 9; x++) R[x] = rot[t * 9 + x];
    #pragma unroll
    for (int x = 0; x < 3; x++) T3[x] = trans[t * 3 + x];
    __syncthreads();

    // q -> AP (scaled)
    for (int col = wk; col < 192; col += 16) {
        const int h = col >> 4, c = col & 15;
        AP[(size_t)(h * 28 + c) * NTOK + t] = QK_SCALE * (RAW[(size_t)col * NTOK + t] + bq[col]);
    }
    // k -> BP, v -> VT
    for (int idx = wk; idx < 192; idx += 16) {
        const int h = idx >> 4, c = idx & 15;
        BP[(size_t)(h * 28 + c) * NTOK + t] = RAW[(size_t)(192 + h * 32 + c) * NTOK + t] + bkv[h * 32 + c];
        VT[idx * NTOK + t] = RAW[(size_t)(192 + h * 32 + 16 + c) * NTOK + t] + bkv[h * 32 + 16 + c];
    }
    // q points: pidx = h*4+p -> QP + AP (hw-scaled)
    for (int pidx = wk; pidx < 48; pidx += 16) {
        const int h = pidx >> 2, p = pidx & 3;
        const float r0 = RAW[(size_t)(576 + 0 * 48 + pidx) * NTOK + t] + bqp[0 * 48 + pidx];
        const float r1 = RAW[(size_t)(576 + 1 * 48 + pidx) * NTOK + t] + bqp[1 * 48 + pidx];
        const float r2 = RAW[(size_t)(576 + 2 * 48 + pidx) * NTOK + t] + bqp[2 * 48 + pidx];
        #pragma unroll
        for (int x = 0; x < 3; x++) {
            const float v = R[x*3+0]*r0 + R[x*3+1]*r1 + R[x*3+2]*r2 + T3[x];
            QP[t * 144 + pidx * 3 + x] = v;
            AP[(size_t)(h * 28 + 16 + p * 3 + x) * NTOK + t] = hwS[h] * v;
        }
    }
    // kv points: pidx = h*12+pp; pp<4 -> BP (kp), else -> VPT
    for (int pidx = wk; pidx < 144; pidx += 16) {
        const int h = pidx / 12, pp = pidx % 12;
        const float r0 = RAW[(size_t)(720 + 0 * 144 + pidx) * NTOK + t] + bkvp[0 * 144 + pidx];
        const float r1 = RAW[(size_t)(720 + 1 * 144 + pidx) * NTOK + t] + bkvp[1 * 144 + pidx];
        const float r2 = RAW[(size_t)(720 + 2 * 144 + pidx) * NTOK + t] + bkvp[2 * 144 + pidx];
        #pragma unroll
        for (int x = 0; x < 3; x++) {
            const float v = R[x*3+0]*r0 + R[x*3+1]*r1 + R[x*3+2]*r2 + T3[x];
            if (pp < 4) BP[(size_t)(h * 28 + 16 + pp * 3 + x) * NTOK + t] = v;
            else        VPT[((h * 8 + pp - 4) * 3 + x) * NTOK + t] = v;
        }
    }
    __syncthreads();
    // norms (per head, per token)
    if (wk < NH) {
        const int h = wk;
        float sq = 0.f, sk = 0.f;
        #pragma unroll
        for (int d = 0; d < 12; d++) {
            const float a = QP[t * 144 + h * 12 + d];
            sq += a * a;
            const float b = BP[(size_t)(h * 28 + 16 + d) * NTOK + t];
            sk += b * b;
        }
        RQN[h * NTOK + t] = -0.5f * hwS[h] * sq;
        CKN[h * NTOK + t] = -0.5f * hwS[h] * sk;
    }
}

// ---------------------------------------------------------------------------
// K2 (MFMA, fat blocks): one block per row i; weights staged + B-frags built
// ONCE, then loop over 12 j-tiles (144 MFMA/wave). R18 postmortem: 9216 thin
// blocks re-staged weights each -> staging dominated (MfmaUtil 1.6%).
// C/D layout (m89-verified): col = lane&15 (=o), row = (lane>>4)*4+reg (=j).
// ---------------------------------------------------------------------------
__global__ __launch_bounds__(256) void k2_zproj_mfma(
    const float* __restrict__ z, const float* __restrict__ wb, const float* __restrict__ bb,
    const float* __restrict__ wdz, const float* __restrict__ bdz,
    float* __restrict__ BBT, uint32* __restrict__ PZB)
{
    __shared__ __align__(16) unsigned short wB[48 * 136];  // [o][k] bf16, 272B rows
    __shared__ float outS[64][52];                         // [j-local][o] + pad
    __shared__ float bbS[12], bdzS[32];

    const int tid = threadIdx.x;
    const int i   = blockIdx.x;
    const int l   = tid & 63;
    const int jt  = tid >> 6;            // wave id = 16-j sub-tile

    // stage weights as bf16, k-contiguous rows (once per block)
    for (int idx = tid; idx < 48 * 64; idx += 256) {
        const int o = idx >> 6, k2 = (idx & 63) * 2;
        float f0, f1;
        if (o < 12)      { f0 = wb[k2 * 12 + o];         f1 = wb[(k2 + 1) * 12 + o]; }
        else if (o < 44) { f0 = wdz[k2 * 32 + (o - 12)]; f1 = wdz[(k2 + 1) * 32 + (o - 12)]; }
        else             { f0 = 0.f; f1 = 0.f; }
        *(uint32*)&wB[o * 136 + k2] = bf16rn(f0) | (bf16rn(f1) << 16);
    }
    if (tid < 12) bbS[tid] = bb[tid];
    else if (tid >= 32 && tid < 64) bdzS[tid - 32] = bdz[tid - 32];
    __syncthreads();

    // B fragments (once): lane: col = l&15, k = ks*32 + (l>>4)*8
    bf16x8 Bf[3][4];
    #pragma unroll
    for (int t = 0; t < 3; t++)
        #pragma unroll
        for (int ks = 0; ks < 4; ks++)
            Bf[t][ks] = *(const bf16x8*)&wB[(t * 16 + (l & 15)) * 136 + ks * 32 + (l >> 4) * 8];

    for (int j0 = 0; j0 < NTOK; j0 += 64) {
        // A source: row j = j0 + jt*16 + (l&15), k base (l>>4)*8
        const float* zrow = z + ((size_t)i * NTOK + j0 + jt * 16 + (l & 15)) * CZ + (l >> 4) * 8;

        f32x4 acc[3];
        #pragma unroll
        for (int t = 0; t < 3; t++) acc[t] = (f32x4){0.f, 0.f, 0.f, 0.f};

        #pragma unroll
        for (int ks = 0; ks < 4; ks++) {
            const float4 a0 = *(const float4*)&zrow[ks * 32];
            const float4 a1 = *(const float4*)&zrow[ks * 32 + 4];
            union { uint32 u[4]; bf16x8 v; } A;
            A.u[0] = bf16rn(a0.x) | (bf16rn(a0.y) << 16);
            A.u[1] = bf16rn(a0.z) | (bf16rn(a0.w) << 16);
            A.u[2] = bf16rn(a1.x) | (bf16rn(a1.y) << 16);
            A.u[3] = bf16rn(a1.z) | (bf16rn(a1.w) << 16);
            #pragma unroll
            for (int t = 0; t < 3; t++)
                acc[t] = __builtin_amdgcn_mfma_f32_16x16x32_bf16(A.v, Bf[t][ks], acc[t], 0, 0, 0);
        }

        __syncthreads();   // previous tile's epilogue must be done with outS
        // scatter D: lane l, reg v -> j_local = jt*16 + (l>>4)*4 + v, o = t*16 + (l&15)
        #pragma unroll
        for (int t = 0; t < 3; t++) {
            const int o = t * 16 + (l & 15);
            #pragma unroll
            for (int v = 0; v < 4; v++)
                outS[jt * 16 + (l >> 4) * 4 + v][o] = acc[t][v];
        }
        __syncthreads();

        // BBT[i][o][j] f32 (+bias), coalesced over j
        for (int idx = tid; idx < 12 * 64; idx += 256) {
            const int o = idx >> 6, jl = idx & 63;
            BBT[((size_t)i * 12 + o) * NTOK + j0 + jl] = outS[jl][o] + bbS[o];
        }
        // PZB[i][c][j-pair] bf16 (+bias), coalesced over j-pairs
        for (int idx = tid; idx < 32 * 32; idx += 256) {
            const int c = idx >> 5, jp = idx & 31;
            const float f0 = outS[jp * 2][12 + c] + bdzS[c];
            const float f1 = outS[jp * 2 + 1][12 + c] + bdzS[c];
            PZB[(size_t)(i * 32 + c) * 384 + (j0 >> 1) + jp] = bf16rn(f0) | (bf16rn(f1) << 16);
        }
    }
}

// ---------------------------------------------------------------------------
// K3a: logit GEMM per head. LG[i][h][j] = AP_h[i].BP_h[j] + b_scale*BBT
//      + RQN[h][i] + CKN[h][j] + INF*(m_i*m_j - 1).  64x64 tiles, K=28.
// ---------------------------------------------------------------------------
__global__ __launch_bounds__(256) void k3a_logits(
    const float* __restrict__ AP, const float* __restrict__ BP,
    const float* __restrict__ RQN, const float* __restrict__ CKN,
    const float* __restrict__ BBT, const float* __restrict__ mask,
    float* __restrict__ LG)
{
    __shared__ float sA[28][64];
    __shared__ float sB[28][64];
    const int tid = threadIdx.x;
    const int j0 = blockIdx.x * 64;
    const int i0 = blockIdx.y * 64;
    const int h  = blockIdx.z;

    #pragma unroll
    for (int t = 0; t < 7; t++) {
        const int idx = tid + t * 256;
        const int row = idx >> 6, col = idx & 63;
        sA[row][col] = AP[(size_t)(h * 28 + row) * NTOK + i0 + col];
        sB[row][col] = BP[(size_t)(h * 28 + row) * NTOK + j0 + col];
    }
    __syncthreads();

    const int m0 = (tid & 15) * 4;   // i offset
    const int n0 = (tid >> 4) * 4;   // j offset

    float4 acc[4];   // acc[mm] = float4 over j
    #pragma unroll
    for (int mm = 0; mm < 4; mm++) acc[mm] = make_float4(0.f, 0.f, 0.f, 0.f);

    #pragma unroll
    for (int k = 0; k < 28; k++) {
        const float4 av = *(const float4*)&sA[k][m0];
        const float4 bv = *(const float4*)&sB[k][n0];
        acc[0].x += av.x * bv.x; acc[0].y += av.x * bv.y; acc[0].z += av.x * bv.z; acc[0].w += av.x * bv.w;
        acc[1].x += av.y * bv.x; acc[1].y += av.y * bv.y; acc[1].z += av.y * bv.z; acc[1].w += av.y * bv.w;
        acc[2].x += av.z * bv.x; acc[2].y += av.z * bv.y; acc[2].z += av.z * bv.z; acc[2].w += av.z * bv.w;
        acc[3].x += av.w * bv.x; acc[3].y += av.w * bv.y; acc[3].z += av.w * bv.z; acc[3].w += av.w * bv.w;
    }

    const float4 ck = *(const float4*)&CKN[h * NTOK + j0 + n0];
    const float4 mj = *(const float4*)&mask[j0 + n0];
    #pragma unroll
    for (int mm = 0; mm < 4; mm++) {
        const int gi = i0 + m0 + mm;
        const float rq = RQN[h * NTOK + gi];
        const float mi = mask[gi];
        const float4 bb = *(const float4*)&BBT[((size_t)gi * NH + h) * NTOK + j0 + n0];
        float4 o;
        o.x = acc[mm].x + B_SCALE * bb.x + rq + ck.x + INF_ * (mi * mj.x - 1.0f);
        o.y = acc[mm].y + B_SCALE * bb.y + rq + ck.y + INF_ * (mi * mj.y - 1.0f);
        o.z = acc[mm].z + B_SCALE * bb.z + rq + ck.z + INF_ * (mi * mj.z - 1.0f);
        o.w = acc[mm].w + B_SCALE * bb.w + rq + ck.w + INF_ * (mi * mj.w - 1.0f);
        *(float4*)&LG[((size_t)gi * NH + h) * NTOK + j0 + n0] = o;
    }
}

// ---------------------------------------------------------------------------
// K3b: per row i — load logits, softmax (wave=head), wave-cooperative sums.
// ---------------------------------------------------------------------------
__global__ __launch_bounds__(768) void k3b_attn(
    const float* __restrict__ LG,
    const float* __restrict__ VT, const float* __restrict__ VPT,
    const uint32* __restrict__ PZB,
    float* __restrict__ O, float* __restrict__ OPT, float* __restrict__ OPAIR)
{
    __shared__ float LB[NH][NTOK];      // logits -> probs in place
    const int i = blockIdx.x, tid = threadIdx.x;

    #pragma unroll
    for (int hh = 0; hh < NH; hh++)
        LB[hh][tid] = LG[((size_t)i * NH + hh) * NTOK + tid];
    __syncthreads();

    const int h = tid >> 6, l = tid & 63;   // wave w = head w (12 waves exactly)

    // softmax
    {
        float m = -3.0e38f;
        for (int jj = l; jj < NTOK; jj += 64) m = fmaxf(m, LB[h][jj]);
        #pragma unroll
        for (int off = 32; off >= 1; off >>= 1) m = fmaxf(m, __shfl_xor(m, off));
        float ssum = 0.0f;
        for (int jj = l; jj < NTOK; jj += 64) {
            const float e = __expf(LB[h][jj] - m);
            LB[h][jj] = e;
            ssum += e;
        }
        #pragma unroll
        for (int off = 32; off >= 1; off >>= 1) ssum += __shfl_xor(ssum, off);
        const float inv = 1.0f / ssum;
        for (int jj = l; jj < NTOK; jj += 64) LB[h][jj] *= inv;
    }
    __syncthreads();

    // wave-cooperative weighted sums (all loads coalesced)
    #pragma unroll 1
    for (int r = 0; r < 40; r++) {
        const float4* src = (r < 16) ? (const float4*)&VT[(h * 16 + r) * NTOK]
                                     : (const float4*)&VPT[(h * 24 + (r - 16)) * NTOK];
        const float4 v0 = src[l],       p0 = *(const float4*)&LB[h][l * 4];
        const float4 v1 = src[64 + l],  p1 = *(const float4*)&LB[h][256 + l * 4];
        const float4 v2 = src[128 + l], p2 = *(const float4*)&LB[h][512 + l * 4];
        float acc = p0.x*v0.x + p0.y*v0.y + p0.z*v0.z + p0.w*v0.w
                  + p1.x*v1.x + p1.y*v1.y + p1.z*v1.z + p1.w*v1.w
                  + p2.x*v2.x + p2.y*v2.y + p2.z*v2.z + p2.w*v2.w;
        #pragma unroll
        for (int off = 32; off >= 1; off >>= 1) acc += __shfl_xor(acc, off);
        if (l == 0) {
            if (r < 16) O[i * 192 + h * 16 + r] = acc;
            else        OPT[i * 288 + h * 24 + (r - 16)] = acc;
        }
    }
    // o_pair: 32 bf16 rows of PZB[i][c][j] (pairs of adjacent j per u32)
    #pragma unroll 1
    for (int c = 0; c < 32; c++) {
        const uint2* src = (const uint2*)PZB + (size_t)(i * 32 + c) * 192;
        float a = 0.f;
        #pragma unroll
        for (int it = 0; it < 3; it++) {
            const uint2 u = src[it * 64 + l];
            const float4 p = *(const float4*)&LB[h][it * 256 + l * 4];
            a += p.x * bflo(u.x) + p.y * bfhi(u.x)
               + p.z * bflo(u.y) + p.w * bfhi(u.y);
        }
        #pragma unroll
        for (int off = 32; off >= 1; off >>= 1) a += __shfl_xor(a, off);
        if (l == 0) OPAIR[i * 384 + h * 32 + c] = a;
    }
}

// ---------------------------------------------------------------------------
// K4: inverse rotation + norms + concat + final linear (8 tokens/block)
// ---------------------------------------------------------------------------
#define K4T 8
__global__ __launch_bounds__(256) void k4_out(
    const float* __restrict__ O, const float* __restrict__ OPT, const float* __restrict__ OPAIR,
    const float* __restrict__ rot, const float* __restrict__ trans,
    const float* __restrict__ wout, const float* __restrict__ bout,
    float* __restrict__ out)
{
    __shared__ float f[K4T][960];
    const int n0 = blockIdx.x * K4T, tid = threadIdx.x;

    for (int idx = tid; idx < K4T * 192; idx += 256) {
        const int t = idx / 192, k = idx % 192;
        f[t][k] = O[(n0 + t) * 192 + k];
    }
    for (int idx = tid; idx < K4T * 384; idx += 256) {
        const int t = idx / 384, k = idx % 384;
        f[t][576 + k] = OPAIR[(n0 + t) * 384 + k];
    }
    for (int idx = tid; idx < K4T * 96; idx += 256) {
        const int t = idx / 96, hp = idx % 96;
        const int n = n0 + t;
        const float vx = OPT[n * 288 + hp * 3 + 0] - trans[n * 3 + 0];
        const float vy = OPT[n * 288 + hp * 3 + 1] - trans[n * 3 + 1];
        const float vz = OPT[n * 288 + hp * 3 + 2] - trans[n * 3 + 2];
        const float o0 = rot[n*9+0]*vx + rot[n*9+3]*vy + rot[n*9+6]*vz;
        const float o1 = rot[n*9+1]*vx + rot[n*9+4]*vy + rot[n*9+7]*vz;
        const float o2 = rot[n*9+2]*vx + rot[n*9+5]*vy + rot[n*9+8]*vz;
        f[t][192 + hp] = o0;
        f[t][288 + hp] = o1;
        f[t][384 + hp] = o2;
        f[t][480 + hp] = sqrtf(o0*o0 + o1*o1 + o2*o2 + EPS_);
    }
    __syncthreads();

    for (int o = tid; o < 384; o += 256) {
        float acc[K4T];
        #pragma unroll
        for (int t = 0; t < K4T; t++) acc[t] = bout[o];
        for (int k = 0; k < 960; k++) {
            const float wv = wout[k * 384 + o];
            #pragma unroll
            for (int t = 0; t < K4T; t++) acc[t] += f[t][k] * wv;
        }
        #pragma unroll
        for (int t = 0; t < K4T; t++) out[(n0 + t) * 384 + o] = acc[t];
    }
}

// ---------------------------------------------------------------------------
extern "C" void kernel_launch(void* const* d_in, const int* in_sizes, int n_in,
                              void* d_out, int out_size, void* d_ws, size_t ws_size,
                              hipStream_t stream) {
    (void)in_sizes; (void)n_in; (void)out_size; (void)ws_size;
    const float* s     = (const float*)d_in[0];
    const float* z     = (const float*)d_in[1];
    const float* rot   = (const float*)d_in[2];
    const float* trans = (const float*)d_in[3];
    const float* mask  = (const float*)d_in[4];
    const float* wq    = (const float*)d_in[5];
    const float* bq    = (const float*)d_in[6];
    const float* wkv   = (const float*)d_in[7];
    const float* bkv   = (const float*)d_in[8];
    const float* wqp   = (const float*)d_in[9];
    const float* bqp   = (const float*)d_in[10];
    const float* wkvp  = (const float*)d_in[11];
    const float* bkvp  = (const float*)d_in[12];
    const float* wb    = (const float*)d_in[13];
    const float* bb    = (const float*)d_in[14];
    const float* wdz   = (const float*)d_in[15];
    const float* bdz   = (const float*)d_in[16];
    const float* hwts  = (const float*)d_in[17];
    const float* wout  = (const float*)d_in[18];
    const float* bout  = (const float*)d_in[19];
    float* out = (float*)d_out;

    float* ws = (float*)d_ws;
    float* Q     = ws;                       // 147456 (unused, kept for layout)
    float* KT    = Q     + 147456;           // 147456 (unused)
    float* VT    = KT    + 147456;           // 147456
    float* QP    = VT    + 147456;           // 110592
    float* KPT   = QP    + 110592;           // 110592 (unused)
    float* VPT   = KPT   + 110592;           // 221184
    float* O     = VPT   + 221184;           // 147456
    float* OPT   = O     + 147456;           // 221184
    float* OPAIR = OPT   + 221184;           // 294912
    float* BBT   = OPAIR + 294912;           // 7,077,888 floats (28.3 MB)
    uint32* PZB  = (uint32*)(BBT + 7077888); // 768*32*384 u32 (37.7 MB)
    float* AP    = BBT + 7077888 + 9437184;  // 12*28*768 = 258048
    float* BP    = AP  + 258048;             // 258048
    float* RQN   = BP  + 258048;             // 9216
    float* CKN   = RQN + 9216;               // 9216
    float* LG    = CKN + 9216;               // 7,077,888 floats (28.3 MB)
    float* RAW = BBT;   // aliases BBT: dead before k2 runs

    hipLaunchKernelGGL(k1a_gemm, dim3(NTOK / 64, 1152 / 64), dim3(256), 0, stream,
                       s, wq, wkv, wqp, wkvp, RAW);
    hipLaunchKernelGGL(k1b_finish, dim3(NTOK / 16), dim3(256), 0, stream,
                       RAW, rot, trans, bq, bkv, bqp, bkvp, hwts,
                       VT, QP, VPT, AP, BP, RQN, CKN);
    hipLaunchKernelGGL(k2_zproj_mfma, dim3(NTOK), dim3(256), 0, stream,
                       z, wb, bb, wdz, bdz, BBT, PZB);
    hipLaunchKernelGGL(k3a_logits, dim3(NTOK / 64, NTOK / 64, NH), dim3(256), 0, stream,
                       AP, BP, RQN, CKN, BBT, mask, LG);
    hipLaunchKernelGGL(k3b_attn, dim3(NTOK), dim3(768), 0, stream,
                       LG, VT, VPT, PZB, O, OPT, OPAIR);
    hipLaunchKernelGGL(k4_out, dim3(NTOK / K4T), dim3(256), 0, stream,
                       O, OPT, OPAIR, rot, trans, wout, bout, out);
}

// Round 20
// 394.099 us; speedup vs baseline: 1.3221x; 1.0479x over previous
//
#include <hip/hip_runtime.h>
#include <math.h>

#define NTOK 768
#define CS   384
#define CZ   128
#define NH   12
#define INF_ 100000.0f
#define EPS_ 1e-8f

typedef unsigned int  uint32;
typedef __attribute__((ext_vector_type(8))) short bf16x8;
typedef __attribute__((ext_vector_type(4))) float f32x4;

__device__ __forceinline__ uint32 bf16rn(float x) {
    uint32 u = __float_as_uint(x);
    return (u + 0x7fffu + ((u >> 16) & 1u)) >> 16;
}
__device__ __forceinline__ float bflo(uint32 u) { return __uint_as_float((u & 0xffffu) << 16); }
__device__ __forceinline__ float bfhi(uint32 u) { return __uint_as_float(u & 0xffff0000u); }

#define QK_SCALE 0.14433756729740643f   // sqrt(1/48)
#define B_SCALE  0.5773502691896258f    // sqrt(1/3)
#define HW_SCALE 0.13608276348795434f   // sqrt(1/54)

// ---------------------------------------------------------------------------
// K1a: tiled GEMM. RAW[col][tok] = sum_k s[tok][k] * Wcat[k][col]  (no bias).
// ---------------------------------------------------------------------------
__global__ __launch_bounds__(256) void k1a_gemm(
    const float* __restrict__ s,
    const float* __restrict__ wq, const float* __restrict__ wkv,
    const float* __restrict__ wqp, const float* __restrict__ wkvp,
    float* __restrict__ RAW)
{
    __shared__ float sA[32][72];   // [k][m]
    __shared__ float sB[32][72];   // [k][n]
    const int tid  = threadIdx.x;
    const int tok0 = blockIdx.x * 64;
    const int col0 = blockIdx.y * 64;

    const int m0 = (tid & 15) * 4;
    const int n0 = (tid >> 4) * 4;

    float4 acc[4];
    #pragma unroll
    for (int nn = 0; nn < 4; nn++) acc[nn] = make_float4(0.f, 0.f, 0.f, 0.f);

    const int lam = tid >> 2, lak = (tid & 3) * 8;
    const int lbk = tid >> 3, lbc = (tid & 7) * 8;
    const int gcol = col0 + lbc;
    const float* wsrc; int wwidth, woff;
    if (gcol < 192)      { wsrc = wq;   wwidth = 192; woff = gcol; }
    else if (gcol < 576) { wsrc = wkv;  wwidth = 384; woff = gcol - 192; }
    else if (gcol < 720) { wsrc = wqp;  wwidth = 144; woff = gcol - 576; }
    else                 { wsrc = wkvp; wwidth = 432; woff = gcol - 720; }

    for (int kb = 0; kb < CS; kb += 32) {
        const float4 a0 = *(const float4*)&s[(tok0 + lam) * CS + kb + lak];
        const float4 a1 = *(const float4*)&s[(tok0 + lam) * CS + kb + lak + 4];
        const float4 b0 = *(const float4*)&wsrc[(size_t)(kb + lbk) * wwidth + woff];
        const float4 b1 = *(const float4*)&wsrc[(size_t)(kb + lbk) * wwidth + woff + 4];
        __syncthreads();
        sA[lak + 0][lam] = a0.x; sA[lak + 1][lam] = a0.y;
        sA[lak + 2][lam] = a0.z; sA[lak + 3][lam] = a0.w;
        sA[lak + 4][lam] = a1.x; sA[lak + 5][lam] = a1.y;
        sA[lak + 6][lam] = a1.z; sA[lak + 7][lam] = a1.w;
        *(float4*)&sB[lbk][lbc]     = b0;
        *(float4*)&sB[lbk][lbc + 4] = b1;
        __syncthreads();
        #pragma unroll
        for (int k = 0; k < 32; k++) {
            const float4 av = *(const float4*)&sA[k][m0];
            const float4 bv = *(const float4*)&sB[k][n0];
            acc[0].x += av.x * bv.x; acc[0].y += av.y * bv.x; acc[0].z += av.z * bv.x; acc[0].w += av.w * bv.x;
            acc[1].x += av.x * bv.y; acc[1].y += av.y * bv.y; acc[1].z += av.z * bv.y; acc[1].w += av.w * bv.y;
            acc[2].x += av.x * bv.z; acc[2].y += av.y * bv.z; acc[2].z += av.z * bv.z; acc[2].w += av.w * bv.z;
            acc[3].x += av.x * bv.w; acc[3].y += av.y * bv.w; acc[3].z += av.z * bv.w; acc[3].w += av.w * bv.w;
        }
    }
    #pragma unroll
    for (int nn = 0; nn < 4; nn++)
        *(float4*)&RAW[(size_t)(col0 + n0 + nn) * NTOK + tok0 + m0] = acc[nn];
}

// ---------------------------------------------------------------------------
// K1b: bias + rigid transform + GEMM-operand packing for the logit GEMM.
// ---------------------------------------------------------------------------
__global__ __launch_bounds__(256) void k1b_finish(
    const float* __restrict__ RAW,
    const float* __restrict__ rot, const float* __restrict__ trans,
    const float* __restrict__ bq, const float* __restrict__ bkv,
    const float* __restrict__ bqp, const float* __restrict__ bkvp,
    const float* __restrict__ head_weights,
    float* __restrict__ VT, float* __restrict__ QP, float* __restrict__ VPT,
    float* __restrict__ AP, float* __restrict__ BP,
    float* __restrict__ RQN, float* __restrict__ CKN)
{
    __shared__ float hwS[NH];
    const int tid = threadIdx.x;
    const int t  = blockIdx.x * 16 + (tid & 15);
    const int wk = tid >> 4;                      // 16 walkers

    if (tid < NH) hwS[tid] = logf(1.0f + expf(head_weights[tid])) * HW_SCALE;

    float R[9], T3[3];
    #pragma unroll
    for (int x = 0; x < 9; x++) R[x] = rot[t * 9 + x];
    #pragma unroll
    for (int x = 0; x < 3; x++) T3[x] = trans[t * 3 + x];
    __syncthreads();

    // q -> AP (scaled)
    for (int col = wk; col < 192; col += 16) {
        const int h = col >> 4, c = col & 15;
        AP[(size_t)(h * 28 + c) * NTOK + t] = QK_SCALE * (RAW[(size_t)col * NTOK + t] + bq[col]);
    }
    // k -> BP, v -> VT
    for (int idx = wk; idx < 192; idx += 16) {
        const int h = idx >> 4, c = idx & 15;
        BP[(size_t)(h * 28 + c) * NTOK + t] = RAW[(size_t)(192 + h * 32 + c) * NTOK + t] + bkv[h * 32 + c];
        VT[idx * NTOK + t] = RAW[(size_t)(192 + h * 32 + 16 + c) * NTOK + t] + bkv[h * 32 + 16 + c];
    }
    // q points: pidx = h*4+p -> QP + AP (hw-scaled)
    for (int pidx = wk; pidx < 48; pidx += 16) {
        const int h = pidx >> 2, p = pidx & 3;
        const float r0 = RAW[(size_t)(576 + 0 * 48 + pidx) * NTOK + t] + bqp[0 * 48 + pidx];
        const float r1 = RAW[(size_t)(576 + 1 * 48 + pidx) * NTOK + t] + bqp[1 * 48 + pidx];
        const float r2 = RAW[(size_t)(576 + 2 * 48 + pidx) * NTOK + t] + bqp[2 * 48 + pidx];
        #pragma unroll
        for (int x = 0; x < 3; x++) {
            const float v = R[x*3+0]*r0 + R[x*3+1]*r1 + R[x*3+2]*r2 + T3[x];
            QP[t * 144 + pidx * 3 + x] = v;
            AP[(size_t)(h * 28 + 16 + p * 3 + x) * NTOK + t] = hwS[h] * v;
        }
    }
    // kv points: pidx = h*12+pp; pp<4 -> BP (kp), else -> VPT
    for (int pidx = wk; pidx < 144; pidx += 16) {
        const int h = pidx / 12, pp = pidx % 12;
        const float r0 = RAW[(size_t)(720 + 0 * 144 + pidx) * NTOK + t] + bkvp[0 * 144 + pidx];
        const float r1 = RAW[(size_t)(720 + 1 * 144 + pidx) * NTOK + t] + bkvp[1 * 144 + pidx];
        const float r2 = RAW[(size_t)(720 + 2 * 144 + pidx) * NTOK + t] + bkvp[2 * 144 + pidx];
        #pragma unroll
        for (int x = 0; x < 3; x++) {
            const float v = R[x*3+0]*r0 + R[x*3+1]*r1 + R[x*3+2]*r2 + T3[x];
            if (pp < 4) BP[(size_t)(h * 28 + 16 + pp * 3 + x) * NTOK + t] = v;
            else        VPT[((h * 8 + pp - 4) * 3 + x) * NTOK + t] = v;
        }
    }
    __syncthreads();
    // norms (per head, per token)
    if (wk < NH) {
        const int h = wk;
        float sq = 0.f, sk = 0.f;
        #pragma unroll
        for (int d = 0; d < 12; d++) {
            const float a = QP[t * 144 + h * 12 + d];
            sq += a * a;
            const float b = BP[(size_t)(h * 28 + 16 + d) * NTOK + t];
            sk += b * b;
        }
        RQN[h * NTOK + t] = -0.5f * hwS[h] * sq;
        CKN[h * NTOK + t] = -0.5f * hwS[h] * sk;
    }
}

// ---------------------------------------------------------------------------
// K2 (MFMA, fat blocks): one block per row i; weights staged + B-frags built
// ONCE, loop over 12 j-tiles. Double-buffered outS -> ONE barrier per tile
// (R19: 2 barriers/tile; buffer alternation makes cross-tile reuse safe
// transitively through the single barrier).
// C/D layout (m89-verified): col = lane&15 (=o), row = (lane>>4)*4+reg (=j).
// ---------------------------------------------------------------------------
__global__ __launch_bounds__(256) void k2_zproj_mfma(
    const float* __restrict__ z, const float* __restrict__ wb, const float* __restrict__ bb,
    const float* __restrict__ wdz, const float* __restrict__ bdz,
    float* __restrict__ BBT, uint32* __restrict__ PZB)
{
    __shared__ __align__(16) unsigned short wB[48 * 136];  // [o][k] bf16, 272B rows
    __shared__ float outS[2][64][52];                      // double-buffered [j-local][o]
    __shared__ float bbS[12], bdzS[32];

    const int tid = threadIdx.x;
    const int i   = blockIdx.x;
    const int l   = tid & 63;
    const int jt  = tid >> 6;            // wave id = 16-j sub-tile

    // stage weights as bf16, k-contiguous rows (once per block)
    for (int idx = tid; idx < 48 * 64; idx += 256) {
        const int o = idx >> 6, k2 = (idx & 63) * 2;
        float f0, f1;
        if (o < 12)      { f0 = wb[k2 * 12 + o];         f1 = wb[(k2 + 1) * 12 + o]; }
        else if (o < 44) { f0 = wdz[k2 * 32 + (o - 12)]; f1 = wdz[(k2 + 1) * 32 + (o - 12)]; }
        else             { f0 = 0.f; f1 = 0.f; }
        *(uint32*)&wB[o * 136 + k2] = bf16rn(f0) | (bf16rn(f1) << 16);
    }
    if (tid < 12) bbS[tid] = bb[tid];
    else if (tid >= 32 && tid < 64) bdzS[tid - 32] = bdz[tid - 32];
    __syncthreads();

    // B fragments (once): lane: col = l&15, k = ks*32 + (l>>4)*8
    bf16x8 Bf[3][4];
    #pragma unroll
    for (int t = 0; t < 3; t++)
        #pragma unroll
        for (int ks = 0; ks < 4; ks++)
            Bf[t][ks] = *(const bf16x8*)&wB[(t * 16 + (l & 15)) * 136 + ks * 32 + (l >> 4) * 8];

    for (int tile = 0; tile < 12; tile++) {
        const int j0  = tile * 64;
        const int buf = tile & 1;
        // A source: row j = j0 + jt*16 + (l&15), k base (l>>4)*8
        const float* zrow = z + ((size_t)i * NTOK + j0 + jt * 16 + (l & 15)) * CZ + (l >> 4) * 8;

        f32x4 acc[3];
        #pragma unroll
        for (int t = 0; t < 3; t++) acc[t] = (f32x4){0.f, 0.f, 0.f, 0.f};

        #pragma unroll
        for (int ks = 0; ks < 4; ks++) {
            const float4 a0 = *(const float4*)&zrow[ks * 32];
            const float4 a1 = *(const float4*)&zrow[ks * 32 + 4];
            union { uint32 u[4]; bf16x8 v; } A;
            A.u[0] = bf16rn(a0.x) | (bf16rn(a0.y) << 16);
            A.u[1] = bf16rn(a0.z) | (bf16rn(a0.w) << 16);
            A.u[2] = bf16rn(a1.x) | (bf16rn(a1.y) << 16);
            A.u[3] = bf16rn(a1.z) | (bf16rn(a1.w) << 16);
            #pragma unroll
            for (int t = 0; t < 3; t++)
                acc[t] = __builtin_amdgcn_mfma_f32_16x16x32_bf16(A.v, Bf[t][ks], acc[t], 0, 0, 0);
        }

        // scatter D: lane l, reg v -> j_local = jt*16 + (l>>4)*4 + v, o = t*16 + (l&15)
        // (safe vs. previous tile's epilogue: different buffer; same-buffer reuse
        //  is ordered by the barrier two iterations ago)
        #pragma unroll
        for (int t = 0; t < 3; t++) {
            const int o = t * 16 + (l & 15);
            #pragma unroll
            for (int v = 0; v < 4; v++)
                outS[buf][jt * 16 + (l >> 4) * 4 + v][o] = acc[t][v];
        }
        __syncthreads();

        // BBT[i][o][j] f32 (+bias), coalesced over j
        for (int idx = tid; idx < 12 * 64; idx += 256) {
            const int o = idx >> 6, jl = idx & 63;
            BBT[((size_t)i * 12 + o) * NTOK + j0 + jl] = outS[buf][jl][o] + bbS[o];
        }
        // PZB[i][c][j-pair] bf16 (+bias), coalesced over j-pairs
        for (int idx = tid; idx < 32 * 32; idx += 256) {
            const int c = idx >> 5, jp = idx & 31;
            const float f0 = outS[buf][jp * 2][12 + c] + bdzS[c];
            const float f1 = outS[buf][jp * 2 + 1][12 + c] + bdzS[c];
            PZB[(size_t)(i * 32 + c) * 384 + (j0 >> 1) + jp] = bf16rn(f0) | (bf16rn(f1) << 16);
        }
    }
}

// ---------------------------------------------------------------------------
// K3a: logit GEMM per head. LG[i][h][j] = AP_h[i].BP_h[j] + b_scale*BBT
//      + RQN[h][i] + CKN[h][j] + INF*(m_i*m_j - 1).  64x64 tiles, K=28.
// ---------------------------------------------------------------------------
__global__ __launch_bounds__(256) void k3a_logits(
    const float* __restrict__ AP, const float* __restrict__ BP,
    const float* __restrict__ RQN, const float* __restrict__ CKN,
    const float* __restrict__ BBT, const float* __restrict__ mask,
    float* __restrict__ LG)
{
    __shared__ float sA[28][64];
    __shared__ float sB[28][64];
    const int tid = threadIdx.x;
    const int j0 = blockIdx.x * 64;
    const int i0 = blockIdx.y * 64;
    const int h  = blockIdx.z;

    #pragma unroll
    for (int t = 0; t < 7; t++) {
        const int idx = tid + t * 256;
        const int row = idx >> 6, col = idx & 63;
        sA[row][col] = AP[(size_t)(h * 28 + row) * NTOK + i0 + col];
        sB[row][col] = BP[(size_t)(h * 28 + row) * NTOK + j0 + col];
    }
    __syncthreads();

    const int m0 = (tid & 15) * 4;   // i offset
    const int n0 = (tid >> 4) * 4;   // j offset

    float4 acc[4];   // acc[mm] = float4 over j
    #pragma unroll
    for (int mm = 0; mm < 4; mm++) acc[mm] = make_float4(0.f, 0.f, 0.f, 0.f);

    #pragma unroll
    for (int k = 0; k < 28; k++) {
        const float4 av = *(const float4*)&sA[k][m0];
        const float4 bv = *(const float4*)&sB[k][n0];
        acc[0].x += av.x * bv.x; acc[0].y += av.x * bv.y; acc[0].z += av.x * bv.z; acc[0].w += av.x * bv.w;
        acc[1].x += av.y * bv.x; acc[1].y += av.y * bv.y; acc[1].z += av.y * bv.z; acc[1].w += av.y * bv.w;
        acc[2].x += av.z * bv.x; acc[2].y += av.z * bv.y; acc[2].z += av.z * bv.z; acc[2].w += av.z * bv.w;
        acc[3].x += av.w * bv.x; acc[3].y += av.w * bv.y; acc[3].z += av.w * bv.z; acc[3].w += av.w * bv.w;
    }

    const float4 ck = *(const float4*)&CKN[h * NTOK + j0 + n0];
    const float4 mj = *(const float4*)&mask[j0 + n0];
    #pragma unroll
    for (int mm = 0; mm < 4; mm++) {
        const int gi = i0 + m0 + mm;
        const float rq = RQN[h * NTOK + gi];
        const float mi = mask[gi];
        const float4 bb = *(const float4*)&BBT[((size_t)gi * NH + h) * NTOK + j0 + n0];
        float4 o;
        o.x = acc[mm].x + B_SCALE * bb.x + rq + ck.x + INF_ * (mi * mj.x - 1.0f);
        o.y = acc[mm].y + B_SCALE * bb.y + rq + ck.y + INF_ * (mi * mj.y - 1.0f);
        o.z = acc[mm].z + B_SCALE * bb.z + rq + ck.z + INF_ * (mi * mj.z - 1.0f);
        o.w = acc[mm].w + B_SCALE * bb.w + rq + ck.w + INF_ * (mi * mj.w - 1.0f);
        *(float4*)&LG[((size_t)gi * NH + h) * NTOK + j0 + n0] = o;
    }
}

// ---------------------------------------------------------------------------
// K3b: per row i — load logits, softmax (wave=head), wave-cooperative sums.
// unroll 2 on phase-4 loops: 2 independent load+shfl chains in flight
// (R19: unroll 1 serialized 72 dependent reductions per wave).
// ---------------------------------------------------------------------------
__global__ __launch_bounds__(768) void k3b_attn(
    const float* __restrict__ LG,
    const float* __restrict__ VT, const float* __restrict__ VPT,
    const uint32* __restrict__ PZB,
    float* __restrict__ O, float* __restrict__ OPT, float* __restrict__ OPAIR)
{
    __shared__ float LB[NH][NTOK];      // logits -> probs in place
    const int i = blockIdx.x, tid = threadIdx.x;

    #pragma unroll
    for (int hh = 0; hh < NH; hh++)
        LB[hh][tid] = LG[((size_t)i * NH + hh) * NTOK + tid];
    __syncthreads();

    const int h = tid >> 6, l = tid & 63;   // wave w = head w (12 waves exactly)

    // softmax
    {
        float m = -3.0e38f;
        for (int jj = l; jj < NTOK; jj += 64) m = fmaxf(m, LB[h][jj]);
        #pragma unroll
        for (int off = 32; off >= 1; off >>= 1) m = fmaxf(m, __shfl_xor(m, off));
        float ssum = 0.0f;
        for (int jj = l; jj < NTOK; jj += 64) {
            const float e = __expf(LB[h][jj] - m);
            LB[h][jj] = e;
            ssum += e;
        }
        #pragma unroll
        for (int off = 32; off >= 1; off >>= 1) ssum += __shfl_xor(ssum, off);
        const float inv = 1.0f / ssum;
        for (int jj = l; jj < NTOK; jj += 64) LB[h][jj] *= inv;
    }
    __syncthreads();

    // wave-cooperative weighted sums (all loads coalesced)
    #pragma unroll 2
    for (int r = 0; r < 40; r++) {
        const float4* src = (r < 16) ? (const float4*)&VT[(h * 16 + r) * NTOK]
                                     : (const float4*)&VPT[(h * 24 + (r - 16)) * NTOK];
        const float4 v0 = src[l],       p0 = *(const float4*)&LB[h][l * 4];
        const float4 v1 = src[64 + l],  p1 = *(const float4*)&LB[h][256 + l * 4];
        const float4 v2 = src[128 + l], p2 = *(const float4*)&LB[h][512 + l * 4];
        float acc = p0.x*v0.x + p0.y*v0.y + p0.z*v0.z + p0.w*v0.w
                  + p1.x*v1.x + p1.y*v1.y + p1.z*v1.z + p1.w*v1.w
                  + p2.x*v2.x + p2.y*v2.y + p2.z*v2.z + p2.w*v2.w;
        #pragma unroll
        for (int off = 32; off >= 1; off >>= 1) acc += __shfl_xor(acc, off);
        if (l == 0) {
            if (r < 16) O[i * 192 + h * 16 + r] = acc;
            else        OPT[i * 288 + h * 24 + (r - 16)] = acc;
        }
    }
    // o_pair: 32 bf16 rows of PZB[i][c][j] (pairs of adjacent j per u32)
    #pragma unroll 2
    for (int c = 0; c < 32; c++) {
        const uint2* src = (const uint2*)PZB + (size_t)(i * 32 + c) * 192;
        float a = 0.f;
        #pragma unroll
        for (int it = 0; it < 3; it++) {
            const uint2 u = src[it * 64 + l];
            const float4 p = *(const float4*)&LB[h][it * 256 + l * 4];
            a += p.x * bflo(u.x) + p.y * bfhi(u.x)
               + p.z * bflo(u.y) + p.w * bfhi(u.y);
        }
        #pragma unroll
        for (int off = 32; off >= 1; off >>= 1) a += __shfl_xor(a, off);
        if (l == 0) OPAIR[i * 384 + h * 32 + c] = a;
    }
}

// ---------------------------------------------------------------------------
// K4: inverse rotation + norms + concat + final linear (8 tokens/block).
// GEMM loop reads f via ds_read_b128 (4 k's per LDS instr): 1920 DS instr
// per thread instead of 7680 (R19: 8x ds_read_b32 per k was LDS-issue-bound).
// ---------------------------------------------------------------------------
#define K4T 8
__global__ __launch_bounds__(256) void k4_out(
    const float* __restrict__ O, const float* __restrict__ OPT, const float* __restrict__ OPAIR,
    const float* __restrict__ rot, const float* __restrict__ trans,
    const float* __restrict__ wout, const float* __restrict__ bout,
    float* __restrict__ out)
{
    __shared__ float f[K4T][960];
    const int n0 = blockIdx.x * K4T, tid = threadIdx.x;

    for (int idx = tid; idx < K4T * 192; idx += 256) {
        const int t = idx / 192, k = idx % 192;
        f[t][k] = O[(n0 + t) * 192 + k];
    }
    for (int idx = tid; idx < K4T * 384; idx += 256) {
        const int t = idx / 384, k = idx % 384;
        f[t][576 + k] = OPAIR[(n0 + t) * 384 + k];
    }
    for (int idx = tid; idx < K4T * 96; idx += 256) {
        const int t = idx / 96, hp = idx % 96;
        const int n = n0 + t;
        const float vx = OPT[n * 288 + hp * 3 + 0] - trans[n * 3 + 0];
        const float vy = OPT[n * 288 + hp * 3 + 1] - trans[n * 3 + 1];
        const float vz = OPT[n * 288 + hp * 3 + 2] - trans[n * 3 + 2];
        const float o0 = rot[n*9+0]*vx + rot[n*9+3]*vy + rot[n*9+6]*vz;
        const float o1 = rot[n*9+1]*vx + rot[n*9+4]*vy + rot[n*9+7]*vz;
        const float o2 = rot[n*9+2]*vx + rot[n*9+5]*vy + rot[n*9+8]*vz;
        f[t][192 + hp] = o0;
        f[t][288 + hp] = o1;
        f[t][384 + hp] = o2;
        f[t][480 + hp] = sqrtf(o0*o0 + o1*o1 + o2*o2 + EPS_);
    }
    __syncthreads();

    for (int o = tid; o < 384; o += 256) {
        float acc[K4T];
        #pragma unroll
        for (int t = 0; t < K4T; t++) acc[t] = bout[o];
        for (int kq = 0; kq < 240; kq++) {
            float4 fv[K4T];
            #pragma unroll
            for (int t = 0; t < K4T; t++) fv[t] = *(const float4*)&f[t][kq * 4];
            #pragma unroll
            for (int kk = 0; kk < 4; kk++) {
                const float wv = wout[(kq * 4 + kk) * 384 + o];
                #pragma unroll
                for (int t = 0; t < K4T; t++) {
                    const float fe = (kk == 0) ? fv[t].x : (kk == 1) ? fv[t].y
                                   : (kk == 2) ? fv[t].z : fv[t].w;
                    acc[t] += fe * wv;
                }
            }
        }
        #pragma unroll
        for (int t = 0; t < K4T; t++) out[(n0 + t) * 384 + o] = acc[t];
    }
}

// ---------------------------------------------------------------------------
extern "C" void kernel_launch(void* const* d_in, const int* in_sizes, int n_in,
                              void* d_out, int out_size, void* d_ws, size_t ws_size,
                              hipStream_t stream) {
    (void)in_sizes; (void)n_in; (void)out_size; (void)ws_size;
    const float* s     = (const float*)d_in[0];
    const float* z     = (const float*)d_in[1];
    const float* rot   = (const float*)d_in[2];
    const float* trans = (const float*)d_in[3];
    const float* mask  = (const float*)d_in[4];
    const float* wq    = (const float*)d_in[5];
    const float* bq    = (const float*)d_in[6];
    const float* wkv   = (const float*)d_in[7];
    const float* bkv   = (const float*)d_in[8];
    const float* wqp   = (const float*)d_in[9];
    const float* bqp   = (const float*)d_in[10];
    const float* wkvp  = (const float*)d_in[11];
    const float* bkvp  = (const float*)d_in[12];
    const float* wb    = (const float*)d_in[13];
    const float* bb    = (const float*)d_in[14];
    const float* wdz   = (const float*)d_in[15];
    const float* bdz   = (const float*)d_in[16];
    const float* hwts  = (const float*)d_in[17];
    const float* wout  = (const float*)d_in[18];
    const float* bout  = (const float*)d_in[19];
    float* out = (float*)d_out;

    float* ws = (float*)d_ws;
    float* Q     = ws;                       // 147456 (unused, kept for layout)
    float* KT    = Q     + 147456;           // 147456 (unused)
    float* VT    = KT    + 147456;           // 147456
    float* QP    = VT    + 147456;           // 110592
    float* KPT   = QP    + 110592;           // 110592 (unused)
    float* VPT   = KPT   + 110592;           // 221184
    float* O     = VPT   + 221184;           // 147456
    float* OPT   = O     + 147456;           // 221184
    float* OPAIR = OPT   + 221184;           // 294912
    float* BBT   = OPAIR + 294912;           // 7,077,888 floats (28.3 MB)
    uint32* PZB  = (uint32*)(BBT + 7077888); // 768*32*384 u32 (37.7 MB)
    float* AP    = BBT + 7077888 + 9437184;  // 12*28*768 = 258048
    float* BP    = AP  + 258048;             // 258048
    float* RQN   = BP  + 258048;             // 9216
    float* CKN   = RQN + 9216;               // 9216
    float* LG    = CKN + 9216;               // 7,077,888 floats (28.3 MB)
    float* RAW = BBT;   // aliases BBT: dead before k2 runs

    hipLaunchKernelGGL(k1a_gemm, dim3(NTOK / 64, 1152 / 64), dim3(256), 0, stream,
                       s, wq, wkv, wqp, wkvp, RAW);
    hipLaunchKernelGGL(k1b_finish, dim3(NTOK / 16), dim3(256), 0, stream,
                       RAW, rot, trans, bq, bkv, bqp, bkvp, hwts,
                       VT, QP, VPT, AP, BP, RQN, CKN);
    hipLaunchKernelGGL(k2_zproj_mfma, dim3(NTOK), dim3(256), 0, stream,
                       z, wb, bb, wdz, bdz, BBT, PZB);
    hipLaunchKernelGGL(k3a_logits, dim3(NTOK / 64, NTOK / 64, NH), dim3(256), 0, stream,
                       AP, BP, RQN, CKN, BBT, mask, LG);
    hipLaunchKernelGGL(k3b_attn, dim3(NTOK), dim3(768), 0, stream,
                       LG, VT, VPT, PZB, O, OPT, OPAIR);
    hipLaunchKernelGGL(k4_out, dim3(NTOK / K4T), dim3(256), 0, stream,
                       O, OPT, OPAIR, rot, trans, wout, bout, out);
}

// Round 21
// 391.433 us; speedup vs baseline: 1.3311x; 1.0068x over previous
//
#include <hip/hip_runtime.h>
#include <hip/hip_bf16.h>
#include <math.h>

#define NTOK 768
#define CS   384
#define CZ   128
#define NH   12
#define INF_ 100000.0f
#define EPS_ 1e-8f

typedef unsigned int  uint32;
typedef __attribute__((ext_vector_type(8))) short bf16x8;
typedef __attribute__((ext_vector_type(4))) float f32x4;

__device__ __forceinline__ uint32 bf16rn(float x) {
    uint32 u = __float_as_uint(x);
    return (u + 0x7fffu + ((u >> 16) & 1u)) >> 16;
}
__device__ __forceinline__ float bflo(uint32 u) { return __uint_as_float((u & 0xffffu) << 16); }
__device__ __forceinline__ float bfhi(uint32 u) { return __uint_as_float(u & 0xffff0000u); }
// scalar-cast pack: compiler emits v_cvt_pk_bf16_f32 (m240: inline-asm/bit-ops defeat it)
__device__ __forceinline__ uint32 pkbf(float a, float b) {
    union { unsigned short s[2]; uint32 u; } r;
    __hip_bfloat16 ha = __float2bfloat16(a);
    __hip_bfloat16 hb = __float2bfloat16(b);
    __builtin_memcpy(&r.s[0], &ha, 2);
    __builtin_memcpy(&r.s[1], &hb, 2);
    return r.u;
}

#define QK_SCALE 0.14433756729740643f   // sqrt(1/48)
#define B_SCALE  0.5773502691896258f    // sqrt(1/3)
#define HW_SCALE 0.13608276348795434f   // sqrt(1/54)

// ---------------------------------------------------------------------------
// K1a: tiled GEMM. RAW[col][tok] = sum_k s[tok][k] * Wcat[k][col]  (no bias).
// ---------------------------------------------------------------------------
__global__ __launch_bounds__(256) void k1a_gemm(
    const float* __restrict__ s,
    const float* __restrict__ wq, const float* __restrict__ wkv,
    const float* __restrict__ wqp, const float* __restrict__ wkvp,
    float* __restrict__ RAW)
{
    __shared__ float sA[32][72];   // [k][m]
    __shared__ float sB[32][72];   // [k][n]
    const int tid  = threadIdx.x;
    const int tok0 = blockIdx.x * 64;
    const int col0 = blockIdx.y * 64;

    const int m0 = (tid & 15) * 4;
    const int n0 = (tid >> 4) * 4;

    float4 acc[4];
    #pragma unroll
    for (int nn = 0; nn < 4; nn++) acc[nn] = make_float4(0.f, 0.f, 0.f, 0.f);

    const int lam = tid >> 2, lak = (tid & 3) * 8;
    const int lbk = tid >> 3, lbc = (tid & 7) * 8;
    const int gcol = col0 + lbc;
    const float* wsrc; int wwidth, woff;
    if (gcol < 192)      { wsrc = wq;   wwidth = 192; woff = gcol; }
    else if (gcol < 576) { wsrc = wkv;  wwidth = 384; woff = gcol - 192; }
    else if (gcol < 720) { wsrc = wqp;  wwidth = 144; woff = gcol - 576; }
    else                 { wsrc = wkvp; wwidth = 432; woff = gcol - 720; }

    for (int kb = 0; kb < CS; kb += 32) {
        const float4 a0 = *(const float4*)&s[(tok0 + lam) * CS + kb + lak];
        const float4 a1 = *(const float4*)&s[(tok0 + lam) * CS + kb + lak + 4];
        const float4 b0 = *(const float4*)&wsrc[(size_t)(kb + lbk) * wwidth + woff];
        const float4 b1 = *(const float4*)&wsrc[(size_t)(kb + lbk) * wwidth + woff + 4];
        __syncthreads();
        sA[lak + 0][lam] = a0.x; sA[lak + 1][lam] = a0.y;
        sA[lak + 2][lam] = a0.z; sA[lak + 3][lam] = a0.w;
        sA[lak + 4][lam] = a1.x; sA[lak + 5][lam] = a1.y;
        sA[lak + 6][lam] = a1.z; sA[lak + 7][lam] = a1.w;
        *(float4*)&sB[lbk][lbc]     = b0;
        *(float4*)&sB[lbk][lbc + 4] = b1;
        __syncthreads();
        #pragma unroll
        for (int k = 0; k < 32; k++) {
            const float4 av = *(const float4*)&sA[k][m0];
            const float4 bv = *(const float4*)&sB[k][n0];
            acc[0].x += av.x * bv.x; acc[0].y += av.y * bv.x; acc[0].z += av.z * bv.x; acc[0].w += av.w * bv.x;
            acc[1].x += av.x * bv.y; acc[1].y += av.y * bv.y; acc[1].z += av.z * bv.y; acc[1].w += av.w * bv.y;
            acc[2].x += av.x * bv.z; acc[2].y += av.y * bv.z; acc[2].z += av.z * bv.z; acc[2].w += av.w * bv.z;
            acc[3].x += av.x * bv.w; acc[3].y += av.y * bv.w; acc[3].z += av.z * bv.w; acc[3].w += av.w * bv.w;
        }
    }
    #pragma unroll
    for (int nn = 0; nn < 4; nn++)
        *(float4*)&RAW[(size_t)(col0 + n0 + nn) * NTOK + tok0 + m0] = acc[nn];
}

// ---------------------------------------------------------------------------
// K1b: bias + rigid transform + GEMM-operand packing for the logit GEMM.
// ---------------------------------------------------------------------------
__global__ __launch_bounds__(256) void k1b_finish(
    const float* __restrict__ RAW,
    const float* __restrict__ rot, const float* __restrict__ trans,
    const float* __restrict__ bq, const float* __restrict__ bkv,
    const float* __restrict__ bqp, const float* __restrict__ bkvp,
    const float* __restrict__ head_weights,
    float* __restrict__ VT, float* __restrict__ QP, float* __restrict__ VPT,
    float* __restrict__ AP, float* __restrict__ BP,
    float* __restrict__ RQN, float* __restrict__ CKN)
{
    __shared__ float hwS[NH];
    const int tid = threadIdx.x;
    const int t  = blockIdx.x * 16 + (tid & 15);
    const int wk = tid >> 4;                      // 16 walkers

    if (tid < NH) hwS[tid] = logf(1.0f + expf(head_weights[tid])) * HW_SCALE;

    float R[9], T3[3];
    #pragma unroll
    for (int x = 0; x < 9; x++) R[x] = rot[t * 9 + x];
    #pragma unroll
    for (int x = 0; x < 3; x++) T3[x] = trans[t * 3 + x];
    __syncthreads();

    // q -> AP (scaled)
    for (int col = wk; col < 192; col += 16) {
        const int h = col >> 4, c = col & 15;
        AP[(size_t)(h * 28 + c) * NTOK + t] = QK_SCALE * (RAW[(size_t)col * NTOK + t] + bq[col]);
    }
    // k -> BP, v -> VT
    for (int idx = wk; idx < 192; idx += 16) {
        const int h = idx >> 4, c = idx & 15;
        BP[(size_t)(h * 28 + c) * NTOK + t] = RAW[(size_t)(192 + h * 32 + c) * NTOK + t] + bkv[h * 32 + c];
        VT[idx * NTOK + t] = RAW[(size_t)(192 + h * 32 + 16 + c) * NTOK + t] + bkv[h * 32 + 16 + c];
    }
    // q points: pidx = h*4+p -> QP + AP (hw-scaled)
    for (int pidx = wk; pidx < 48; pidx += 16) {
        const int h = pidx >> 2, p = pidx & 3;
        const float r0 = RAW[(size_t)(576 + 0 * 48 + pidx) * NTOK + t] + bqp[0 * 48 + pidx];
        const float r1 = RAW[(size_t)(576 + 1 * 48 + pidx) * NTOK + t] + bqp[1 * 48 + pidx];
        const float r2 = RAW[(size_t)(576 + 2 * 48 + pidx) * NTOK + t] + bqp[2 * 48 + pidx];
        #pragma unroll
        for (int x = 0; x < 3; x++) {
            const float v = R[x*3+0]*r0 + R[x*3+1]*r1 + R[x*3+2]*r2 + T3[x];
            QP[t * 144 + pidx * 3 + x] = v;
            AP[(size_t)(h * 28 + 16 + p * 3 + x) * NTOK + t] = hwS[h] * v;
        }
    }
    // kv points: pidx = h*12+pp; pp<4 -> BP (kp), else -> VPT
    for (int pidx = wk; pidx < 144; pidx += 16) {
        const int h = pidx / 12, pp = pidx % 12;
        const float r0 = RAW[(size_t)(720 + 0 * 144 + pidx) * NTOK + t] + bkvp[0 * 144 + pidx];
        const float r1 = RAW[(size_t)(720 + 1 * 144 + pidx) * NTOK + t] + bkvp[1 * 144 + pidx];
        const float r2 = RAW[(size_t)(720 + 2 * 144 + pidx) * NTOK + t] + bkvp[2 * 144 + pidx];
        #pragma unroll
        for (int x = 0; x < 3; x++) {
            const float v = R[x*3+0]*r0 + R[x*3+1]*r1 + R[x*3+2]*r2 + T3[x];
            if (pp < 4) BP[(size_t)(h * 28 + 16 + pp * 3 + x) * NTOK + t] = v;
            else        VPT[((h * 8 + pp - 4) * 3 + x) * NTOK + t] = v;
        }
    }
    __syncthreads();
    // norms (per head, per token)
    if (wk < NH) {
        const int h = wk;
        float sq = 0.f, sk = 0.f;
        #pragma unroll
        for (int d = 0; d < 12; d++) {
            const float a = QP[t * 144 + h * 12 + d];
            sq += a * a;
            const float b = BP[(size_t)(h * 28 + 16 + d) * NTOK + t];
            sk += b * b;
        }
        RQN[h * NTOK + t] = -0.5f * hwS[h] * sq;
        CKN[h * NTOK + t] = -0.5f * hwS[h] * sk;
    }
}

// ---------------------------------------------------------------------------
// K2 (MFMA, fat blocks): one block per row i; weights staged + B-frags built
// ONCE, loop over 12 j-tiles, double-buffered outS (1 barrier/tile).
// R20 changes: (a) A-pack via pkbf (compiler v_cvt_pk_bf16_f32; bf16rn
// bit-ops cost ~4 VALU per value), (b) next tile's A prefetched into regs
// right after the pack so global latency hides under MFMA+epilogue.
// C/D layout (m89-verified): col = lane&15 (=o), row = (lane>>4)*4+reg (=j).
// ---------------------------------------------------------------------------
__global__ __launch_bounds__(256) void k2_zproj_mfma(
    const float* __restrict__ z, const float* __restrict__ wb, const float* __restrict__ bb,
    const float* __restrict__ wdz, const float* __restrict__ bdz,
    float* __restrict__ BBT, uint32* __restrict__ PZB)
{
    __shared__ __align__(16) unsigned short wB[48 * 136];  // [o][k] bf16, 272B rows
    __shared__ float outS[2][64][52];                      // double-buffered [j-local][o]
    __shared__ float bbS[12], bdzS[32];

    const int tid = threadIdx.x;
    const int i   = blockIdx.x;
    const int l   = tid & 63;
    const int jt  = tid >> 6;            // wave id = 16-j sub-tile

    // stage weights as bf16, k-contiguous rows (once per block)
    for (int idx = tid; idx < 48 * 64; idx += 256) {
        const int o = idx >> 6, k2 = (idx & 63) * 2;
        float f0, f1;
        if (o < 12)      { f0 = wb[k2 * 12 + o];         f1 = wb[(k2 + 1) * 12 + o]; }
        else if (o < 44) { f0 = wdz[k2 * 32 + (o - 12)]; f1 = wdz[(k2 + 1) * 32 + (o - 12)]; }
        else             { f0 = 0.f; f1 = 0.f; }
        *(uint32*)&wB[o * 136 + k2] = pkbf(f0, f1);
    }
    if (tid < 12) bbS[tid] = bb[tid];
    else if (tid >= 32 && tid < 64) bdzS[tid - 32] = bdz[tid - 32];
    __syncthreads();

    // B fragments (once): lane: col = l&15, k = ks*32 + (l>>4)*8
    bf16x8 Bf[3][4];
    #pragma unroll
    for (int t = 0; t < 3; t++)
        #pragma unroll
        for (int ks = 0; ks < 4; ks++)
            Bf[t][ks] = *(const bf16x8*)&wB[(t * 16 + (l & 15)) * 136 + ks * 32 + (l >> 4) * 8];

    // A base for tile 0: row j = jt*16 + (l&15), k base (l>>4)*8
    const float* zb = z + ((size_t)i * NTOK + jt * 16 + (l & 15)) * CZ + (l >> 4) * 8;

    float4 pa[8];
    #pragma unroll
    for (int ks = 0; ks < 4; ks++) {
        pa[2 * ks]     = *(const float4*)&zb[ks * 32];
        pa[2 * ks + 1] = *(const float4*)&zb[ks * 32 + 4];
    }

    for (int tile = 0; tile < 12; tile++) {
        const int j0  = tile * 64;
        const int buf = tile & 1;

        // pack current tile's A into fragments
        union { uint32 u[4]; bf16x8 v; } Au[4];
        #pragma unroll
        for (int ks = 0; ks < 4; ks++) {
            Au[ks].u[0] = pkbf(pa[2 * ks].x,     pa[2 * ks].y);
            Au[ks].u[1] = pkbf(pa[2 * ks].z,     pa[2 * ks].w);
            Au[ks].u[2] = pkbf(pa[2 * ks + 1].x, pa[2 * ks + 1].y);
            Au[ks].u[3] = pkbf(pa[2 * ks + 1].z, pa[2 * ks + 1].w);
        }
        // prefetch next tile's A (overlaps MFMA + scatter + barrier + epilogue)
        if (tile < 11) {
            const float* zn = zb + (size_t)(tile + 1) * 64 * CZ;
            #pragma unroll
            for (int ks = 0; ks < 4; ks++) {
                pa[2 * ks]     = *(const float4*)&zn[ks * 32];
                pa[2 * ks + 1] = *(const float4*)&zn[ks * 32 + 4];
            }
        }

        f32x4 acc[3];
        #pragma unroll
        for (int t = 0; t < 3; t++) acc[t] = (f32x4){0.f, 0.f, 0.f, 0.f};
        #pragma unroll
        for (int ks = 0; ks < 4; ks++)
            #pragma unroll
            for (int t = 0; t < 3; t++)
                acc[t] = __builtin_amdgcn_mfma_f32_16x16x32_bf16(Au[ks].v, Bf[t][ks], acc[t], 0, 0, 0);

        // scatter D: lane l, reg v -> j_local = jt*16 + (l>>4)*4 + v, o = t*16 + (l&15)
        #pragma unroll
        for (int t = 0; t < 3; t++) {
            const int o = t * 16 + (l & 15);
            #pragma unroll
            for (int v = 0; v < 4; v++)
                outS[buf][jt * 16 + (l >> 4) * 4 + v][o] = acc[t][v];
        }
        __syncthreads();

        // BBT[i][o][j] f32 (+bias), coalesced over j
        for (int idx = tid; idx < 12 * 64; idx += 256) {
            const int o = idx >> 6, jl = idx & 63;
            BBT[((size_t)i * 12 + o) * NTOK + j0 + jl] = outS[buf][jl][o] + bbS[o];
        }
        // PZB[i][c][j-pair] bf16 (+bias), coalesced over j-pairs
        for (int idx = tid; idx < 32 * 32; idx += 256) {
            const int c = idx >> 5, jp = idx & 31;
            const float f0 = outS[buf][jp * 2][12 + c] + bdzS[c];
            const float f1 = outS[buf][jp * 2 + 1][12 + c] + bdzS[c];
            PZB[(size_t)(i * 32 + c) * 384 + (j0 >> 1) + jp] = pkbf(f0, f1);
        }
    }
}

// ---------------------------------------------------------------------------
// K3a: logit GEMM per head. LG[i][h][j] = AP_h[i].BP_h[j] + b_scale*BBT
//      + RQN[h][i] + CKN[h][j] + INF*(m_i*m_j - 1).  64x64 tiles, K=28.
// ---------------------------------------------------------------------------
__global__ __launch_bounds__(256) void k3a_logits(
    const float* __restrict__ AP, const float* __restrict__ BP,
    const float* __restrict__ RQN, const float* __restrict__ CKN,
    const float* __restrict__ BBT, const float* __restrict__ mask,
    float* __restrict__ LG)
{
    __shared__ float sA[28][64];
    __shared__ float sB[28][64];
    const int tid = threadIdx.x;
    const int j0 = blockIdx.x * 64;
    const int i0 = blockIdx.y * 64;
    const int h  = blockIdx.z;

    #pragma unroll
    for (int t = 0; t < 7; t++) {
        const int idx = tid + t * 256;
        const int row = idx >> 6, col = idx & 63;
        sA[row][col] = AP[(size_t)(h * 28 + row) * NTOK + i0 + col];
        sB[row][col] = BP[(size_t)(h * 28 + row) * NTOK + j0 + col];
    }
    __syncthreads();

    const int m0 = (tid & 15) * 4;   // i offset
    const int n0 = (tid >> 4) * 4;   // j offset

    float4 acc[4];   // acc[mm] = float4 over j
    #pragma unroll
    for (int mm = 0; mm < 4; mm++) acc[mm] = make_float4(0.f, 0.f, 0.f, 0.f);

    #pragma unroll
    for (int k = 0; k < 28; k++) {
        const float4 av = *(const float4*)&sA[k][m0];
        const float4 bv = *(const float4*)&sB[k][n0];
        acc[0].x += av.x * bv.x; acc[0].y += av.x * bv.y; acc[0].z += av.x * bv.z; acc[0].w += av.x * bv.w;
        acc[1].x += av.y * bv.x; acc[1].y += av.y * bv.y; acc[1].z += av.y * bv.z; acc[1].w += av.y * bv.w;
        acc[2].x += av.z * bv.x; acc[2].y += av.z * bv.y; acc[2].z += av.z * bv.z; acc[2].w += av.z * bv.w;
        acc[3].x += av.w * bv.x; acc[3].y += av.w * bv.y; acc[3].z += av.w * bv.z; acc[3].w += av.w * bv.w;
    }

    const float4 ck = *(const float4*)&CKN[h * NTOK + j0 + n0];
    const float4 mj = *(const float4*)&mask[j0 + n0];
    #pragma unroll
    for (int mm = 0; mm < 4; mm++) {
        const int gi = i0 + m0 + mm;
        const float rq = RQN[h * NTOK + gi];
        const float mi = mask[gi];
        const float4 bb = *(const float4*)&BBT[((size_t)gi * NH + h) * NTOK + j0 + n0];
        float4 o;
        o.x = acc[mm].x + B_SCALE * bb.x + rq + ck.x + INF_ * (mi * mj.x - 1.0f);
        o.y = acc[mm].y + B_SCALE * bb.y + rq + ck.y + INF_ * (mi * mj.y - 1.0f);
        o.z = acc[mm].z + B_SCALE * bb.z + rq + ck.z + INF_ * (mi * mj.z - 1.0f);
        o.w = acc[mm].w + B_SCALE * bb.w + rq + ck.w + INF_ * (mi * mj.w - 1.0f);
        *(float4*)&LG[((size_t)gi * NH + h) * NTOK + j0 + n0] = o;
    }
}

// ---------------------------------------------------------------------------
// K3b: per row i — load logits, softmax (wave=head), wave-cooperative sums.
// ---------------------------------------------------------------------------
__global__ __launch_bounds__(768) void k3b_attn(
    const float* __restrict__ LG,
    const float* __restrict__ VT, const float* __restrict__ VPT,
    const uint32* __restrict__ PZB,
    float* __restrict__ O, float* __restrict__ OPT, float* __restrict__ OPAIR)
{
    __shared__ float LB[NH][NTOK];      // logits -> probs in place
    const int i = blockIdx.x, tid = threadIdx.x;

    #pragma unroll
    for (int hh = 0; hh < NH; hh++)
        LB[hh][tid] = LG[((size_t)i * NH + hh) * NTOK + tid];
    __syncthreads();

    const int h = tid >> 6, l = tid & 63;   // wave w = head w (12 waves exactly)

    // softmax
    {
        float m = -3.0e38f;
        for (int jj = l; jj < NTOK; jj += 64) m = fmaxf(m, LB[h][jj]);
        #pragma unroll
        for (int off = 32; off >= 1; off >>= 1) m = fmaxf(m, __shfl_xor(m, off));
        float ssum = 0.0f;
        for (int jj = l; jj < NTOK; jj += 64) {
            const float e = __expf(LB[h][jj] - m);
            LB[h][jj] = e;
            ssum += e;
        }
        #pragma unroll
        for (int off = 32; off >= 1; off >>= 1) ssum += __shfl_xor(ssum, off);
        const float inv = 1.0f / ssum;
        for (int jj = l; jj < NTOK; jj += 64) LB[h][jj] *= inv;
    }
    __syncthreads();

    // wave-cooperative weighted sums (all loads coalesced)
    #pragma unroll 2
    for (int r = 0; r < 40; r++) {
        const float4* src = (r < 16) ? (const float4*)&VT[(h * 16 + r) * NTOK]
                                     : (const float4*)&VPT[(h * 24 + (r - 16)) * NTOK];
        const float4 v0 = src[l],       p0 = *(const float4*)&LB[h][l * 4];
        const float4 v1 = src[64 + l],  p1 = *(const float4*)&LB[h][256 + l * 4];
        const float4 v2 = src[128 + l], p2 = *(const float4*)&LB[h][512 + l * 4];
        float acc = p0.x*v0.x + p0.y*v0.y + p0.z*v0.z + p0.w*v0.w
                  + p1.x*v1.x + p1.y*v1.y + p1.z*v1.z + p1.w*v1.w
                  + p2.x*v2.x + p2.y*v2.y + p2.z*v2.z + p2.w*v2.w;
        #pragma unroll
        for (int off = 32; off >= 1; off >>= 1) acc += __shfl_xor(acc, off);
        if (l == 0) {
            if (r < 16) O[i * 192 + h * 16 + r] = acc;
            else        OPT[i * 288 + h * 24 + (r - 16)] = acc;
        }
    }
    // o_pair: 32 bf16 rows of PZB[i][c][j] (pairs of adjacent j per u32)
    #pragma unroll 2
    for (int c = 0; c < 32; c++) {
        const uint2* src = (const uint2*)PZB + (size_t)(i * 32 + c) * 192;
        float a = 0.f;
        #pragma unroll
        for (int it = 0; it < 3; it++) {
            const uint2 u = src[it * 64 + l];
            const float4 p = *(const float4*)&LB[h][it * 256 + l * 4];
            a += p.x * bflo(u.x) + p.y * bfhi(u.x)
               + p.z * bflo(u.y) + p.w * bfhi(u.y);
        }
        #pragma unroll
        for (int off = 32; off >= 1; off >>= 1) a += __shfl_xor(a, off);
        if (l == 0) OPAIR[i * 384 + h * 32 + c] = a;
    }
}

// ---------------------------------------------------------------------------
// K4: inverse rotation + norms + concat + final linear (8 tokens/block).
// GEMM loop reads f via ds_read_b128 (4 k's per LDS instr).
// ---------------------------------------------------------------------------
#define K4T 8
__global__ __launch_bounds__(256) void k4_out(
    const float* __restrict__ O, const float* __restrict__ OPT, const float* __restrict__ OPAIR,
    const float* __restrict__ rot, const float* __restrict__ trans,
    const float* __restrict__ wout, const float* __restrict__ bout,
    float* __restrict__ out)
{
    __shared__ float f[K4T][960];
    const int n0 = blockIdx.x * K4T, tid = threadIdx.x;

    for (int idx = tid; idx < K4T * 192; idx += 256) {
        const int t = idx / 192, k = idx % 192;
        f[t][k] = O[(n0 + t) * 192 + k];
    }
    for (int idx = tid; idx < K4T * 384; idx += 256) {
        const int t = idx / 384, k = idx % 384;
        f[t][576 + k] = OPAIR[(n0 + t) * 384 + k];
    }
    for (int idx = tid; idx < K4T * 96; idx += 256) {
        const int t = idx / 96, hp = idx % 96;
        const int n = n0 + t;
        const float vx = OPT[n * 288 + hp * 3 + 0] - trans[n * 3 + 0];
        const float vy = OPT[n * 288 + hp * 3 + 1] - trans[n * 3 + 1];
        const float vz = OPT[n * 288 + hp * 3 + 2] - trans[n * 3 + 2];
        const float o0 = rot[n*9+0]*vx + rot[n*9+3]*vy + rot[n*9+6]*vz;
        const float o1 = rot[n*9+1]*vx + rot[n*9+4]*vy + rot[n*9+7]*vz;
        const float o2 = rot[n*9+2]*vx + rot[n*9+5]*vy + rot[n*9+8]*vz;
        f[t][192 + hp] = o0;
        f[t][288 + hp] = o1;
        f[t][384 + hp] = o2;
        f[t][480 + hp] = sqrtf(o0*o0 + o1*o1 + o2*o2 + EPS_);
    }
    __syncthreads();

    for (int o = tid; o < 384; o += 256) {
        float acc[K4T];
        #pragma unroll
        for (int t = 0; t < K4T; t++) acc[t] = bout[o];
        for (int kq = 0; kq < 240; kq++) {
            float4 fv[K4T];
            #pragma unroll
            for (int t = 0; t < K4T; t++) fv[t] = *(const float4*)&f[t][kq * 4];
            #pragma unroll
            for (int kk = 0; kk < 4; kk++) {
                const float wv = wout[(kq * 4 + kk) * 384 + o];
                #pragma unroll
                for (int t = 0; t < K4T; t++) {
                    const float fe = (kk == 0) ? fv[t].x : (kk == 1) ? fv[t].y
                                   : (kk == 2) ? fv[t].z : fv[t].w;
                    acc[t] += fe * wv;
                }
            }
        }
        #pragma unroll
        for (int t = 0; t < K4T; t++) out[(n0 + t) * 384 + o] = acc[t];
    }
}

// ---------------------------------------------------------------------------
extern "C" void kernel_launch(void* const* d_in, const int* in_sizes, int n_in,
                              void* d_out, int out_size, void* d_ws, size_t ws_size,
                              hipStream_t stream) {
    (void)in_sizes; (void)n_in; (void)out_size; (void)ws_size;
    const float* s     = (const float*)d_in[0];
    const float* z     = (const float*)d_in[1];
    const float* rot   = (const float*)d_in[2];
    const float* trans = (const float*)d_in[3];
    const float* mask  = (const float*)d_in[4];
    const float* wq    = (const float*)d_in[5];
    const float* bq    = (const float*)d_in[6];
    const float* wkv   = (const float*)d_in[7];
    const float* bkv   = (const float*)d_in[8];
    const float* wqp   = (const float*)d_in[9];
    const float* bqp   = (const float*)d_in[10];
    const float* wkvp  = (const float*)d_in[11];
    const float* bkvp  = (const float*)d_in[12];
    const float* wb    = (const float*)d_in[13];
    const float* bb    = (const float*)d_in[14];
    const float* wdz   = (const float*)d_in[15];
    const float* bdz   = (const float*)d_in[16];
    const float* hwts  = (const float*)d_in[17];
    const float* wout  = (const float*)d_in[18];
    const float* bout  = (const float*)d_in[19];
    float* out = (float*)d_out;

    float* ws = (float*)d_ws;
    float* Q     = ws;                       // 147456 (unused, kept for layout)
    float* KT    = Q     + 147456;           // 147456 (unused)
    float* VT    = KT    + 147456;           // 147456
    float* QP    = VT    + 147456;           // 110592
    float* KPT   = QP    + 110592;           // 110592 (unused)
    float* VPT   = KPT   + 110592;           // 221184
    float* O     = VPT   + 221184;           // 147456
    float* OPT   = O     + 147456;           // 221184
    float* OPAIR = OPT   + 221184;           // 294912
    float* BBT   = OPAIR + 294912;           // 7,077,888 floats (28.3 MB)
    uint32* PZB  = (uint32*)(BBT + 7077888); // 768*32*384 u32 (37.7 MB)
    float* AP    = BBT + 7077888 + 9437184;  // 12*28*768 = 258048
    float* BP    = AP  + 258048;             // 258048
    float* RQN   = BP  + 258048;             // 9216
    float* CKN   = RQN + 9216;               // 9216
    float* LG    = CKN + 9216;               // 7,077,888 floats (28.3 MB)
    float* RAW = BBT;   // aliases BBT: dead before k2 runs

    hipLaunchKernelGGL(k1a_gemm, dim3(NTOK / 64, 1152 / 64), dim3(256), 0, stream,
                       s, wq, wkv, wqp, wkvp, RAW);
    hipLaunchKernelGGL(k1b_finish, dim3(NTOK / 16), dim3(256), 0, stream,
                       RAW, rot, trans, bq, bkv, bqp, bkvp, hwts,
                       VT, QP, VPT, AP, BP, RQN, CKN);
    hipLaunchKernelGGL(k2_zproj_mfma, dim3(NTOK), dim3(256), 0, stream,
                       z, wb, bb, wdz, bdz, BBT, PZB);
    hipLaunchKernelGGL(k3a_logits, dim3(NTOK / 64, NTOK / 64, NH), dim3(256), 0, stream,
                       AP, BP, RQN, CKN, BBT, mask, LG);
    hipLaunchKernelGGL(k3b_attn, dim3(NTOK), dim3(768), 0, stream,
                       LG, VT, VPT, PZB, O, OPT, OPAIR);
    hipLaunchKernelGGL(k4_out, dim3(NTOK / K4T), dim3(256), 0, stream,
                       O, OPT, OPAIR, rot, trans, wout, bout, out);
}

// Round 24
// 383.907 us; speedup vs baseline: 1.3572x; 1.0196x over previous
//
#include <hip/hip_runtime.h>
#include <hip/hip_bf16.h>
#include <math.h>

#define NTOK 768
#define CS   384
#define CZ   128
#define NH   12
#define INF_ 100000.0f
#define EPS_ 1e-8f

typedef unsigned int  uint32;
typedef __attribute__((ext_vector_type(8))) short bf16x8;
typedef __attribute__((ext_vector_type(4))) float f32x4;

__device__ __forceinline__ float bflo(uint32 u) { return __uint_as_float((u & 0xffffu) << 16); }
__device__ __forceinline__ float bfhi(uint32 u) { return __uint_as_float(u & 0xffff0000u); }
// scalar-cast pack: compiler emits v_cvt_pk_bf16_f32
__device__ __forceinline__ uint32 pkbf(float a, float b) {
    union { unsigned short s[2]; uint32 u; } r;
    __hip_bfloat16 ha = __float2bfloat16(a);
    __hip_bfloat16 hb = __float2bfloat16(b);
    __builtin_memcpy(&r.s[0], &ha, 2);
    __builtin_memcpy(&r.s[1], &hb, 2);
    return r.u;
}

#define QK_SCALE 0.14433756729740643f   // sqrt(1/48)
#define B_SCALE  0.5773502691896258f    // sqrt(1/3)
#define HW_SCALE 0.13608276348795434f   // sqrt(1/54)

// ---------------------------------------------------------------------------
// K1a: tiled GEMM. RAW[col][tok] = sum_k s[tok][k] * Wcat[k][col]  (no bias).
// ---------------------------------------------------------------------------
__global__ __launch_bounds__(256) void k1a_gemm(
    const float* __restrict__ s,
    const float* __restrict__ wq, const float* __restrict__ wkv,
    const float* __restrict__ wqp, const float* __restrict__ wkvp,
    float* __restrict__ RAW)
{
    __shared__ float sA[32][72];   // [k][m]
    __shared__ float sB[32][72];   // [k][n]
    const int tid  = threadIdx.x;
    const int tok0 = blockIdx.x * 64;
    const int col0 = blockIdx.y * 64;

    const int m0 = (tid & 15) * 4;
    const int n0 = (tid >> 4) * 4;

    float4 acc[4];
    #pragma unroll
    for (int nn = 0; nn < 4; nn++) acc[nn] = make_float4(0.f, 0.f, 0.f, 0.f);

    const int lam = tid >> 2, lak = (tid & 3) * 8;
    const int lbk = tid >> 3, lbc = (tid & 7) * 8;
    const int gcol = col0 + lbc;
    const float* wsrc; int wwidth, woff;
    if (gcol < 192)      { wsrc = wq;   wwidth = 192; woff = gcol; }
    else if (gcol < 576) { wsrc = wkv;  wwidth = 384; woff = gcol - 192; }
    else if (gcol < 720) { wsrc = wqp;  wwidth = 144; woff = gcol - 576; }
    else                 { wsrc = wkvp; wwidth = 432; woff = gcol - 720; }

    for (int kb = 0; kb < CS; kb += 32) {
        const float4 a0 = *(const float4*)&s[(tok0 + lam) * CS + kb + lak];
        const float4 a1 = *(const float4*)&s[(tok0 + lam) * CS + kb + lak + 4];
        const float4 b0 = *(const float4*)&wsrc[(size_t)(kb + lbk) * wwidth + woff];
        const float4 b1 = *(const float4*)&wsrc[(size_t)(kb + lbk) * wwidth + woff + 4];
        __syncthreads();
        sA[lak + 0][lam] = a0.x; sA[lak + 1][lam] = a0.y;
        sA[lak + 2][lam] = a0.z; sA[lak + 3][lam] = a0.w;
        sA[lak + 4][lam] = a1.x; sA[lak + 5][lam] = a1.y;
        sA[lak + 6][lam] = a1.z; sA[lak + 7][lam] = a1.w;
        *(float4*)&sB[lbk][lbc]     = b0;
        *(float4*)&sB[lbk][lbc + 4] = b1;
        __syncthreads();
        #pragma unroll
        for (int k = 0; k < 32; k++) {
            const float4 av = *(const float4*)&sA[k][m0];
            const float4 bv = *(const float4*)&sB[k][n0];
            acc[0].x += av.x * bv.x; acc[0].y += av.y * bv.x; acc[0].z += av.z * bv.x; acc[0].w += av.w * bv.x;
            acc[1].x += av.x * bv.y; acc[1].y += av.y * bv.y; acc[1].z += av.z * bv.y; acc[1].w += av.w * bv.y;
            acc[2].x += av.x * bv.z; acc[2].y += av.y * bv.z; acc[2].z += av.z * bv.z; acc[2].w += av.w * bv.z;
            acc[3].x += av.x * bv.w; acc[3].y += av.y * bv.w; acc[3].z += av.z * bv.w; acc[3].w += av.w * bv.w;
        }
    }
    #pragma unroll
    for (int nn = 0; nn < 4; nn++)
        *(float4*)&RAW[(size_t)(col0 + n0 + nn) * NTOK + tok0 + m0] = acc[nn];
}

// ---------------------------------------------------------------------------
// K1b: bias + rigid transform + GEMM-operand packing for the logit GEMM.
// ---------------------------------------------------------------------------
__global__ __launch_bounds__(256) void k1b_finish(
    const float* __restrict__ RAW,
    const float* __restrict__ rot, const float* __restrict__ trans,
    const float* __restrict__ bq, const float* __restrict__ bkv,
    const float* __restrict__ bqp, const float* __restrict__ bkvp,
    const float* __restrict__ head_weights,
    float* __restrict__ VT, float* __restrict__ QP, float* __restrict__ VPT,
    float* __restrict__ AP, float* __restrict__ BP,
    float* __restrict__ RQN, float* __restrict__ CKN)
{
    __shared__ float hwS[NH];
    const int tid = threadIdx.x;
    const int t  = blockIdx.x * 16 + (tid & 15);
    const int wk = tid >> 4;                      // 16 walkers

    if (tid < NH) hwS[tid] = logf(1.0f + expf(head_weights[tid])) * HW_SCALE;

    float R[9], T3[3];
    #pragma unroll
    for (int x = 0; x < 9; x++) R[x] = rot[t * 9 + x];
    #pragma unroll
    for (int x = 0; x < 3; x++) T3[x] = trans[t * 3 + x];
    __syncthreads();

    // q -> AP (scaled)
    for (int col = wk; col < 192; col += 16) {
        const int h = col >> 4, c = col & 15;
        AP[(size_t)(h * 28 + c) * NTOK + t] = QK_SCALE * (RAW[(size_t)col * NTOK + t] + bq[col]);
    }
    // k -> BP, v -> VT
    for (int idx = wk; idx < 192; idx += 16) {
        const int h = idx >> 4, c = idx & 15;
        BP[(size_t)(h * 28 + c) * NTOK + t] = RAW[(size_t)(192 + h * 32 + c) * NTOK + t] + bkv[h * 32 + c];
        VT[idx * NTOK + t] = RAW[(size_t)(192 + h * 32 + 16 + c) * NTOK + t] + bkv[h * 32 + 16 + c];
    }
    // q points: pidx = h*4+p -> QP + AP (hw-scaled)
    for (int pidx = wk; pidx < 48; pidx += 16) {
        const int h = pidx >> 2, p = pidx & 3;
        const float r0 = RAW[(size_t)(576 + 0 * 48 + pidx) * NTOK + t] + bqp[0 * 48 + pidx];
        const float r1 = RAW[(size_t)(576 + 1 * 48 + pidx) * NTOK + t] + bqp[1 * 48 + pidx];
        const float r2 = RAW[(size_t)(576 + 2 * 48 + pidx) * NTOK + t] + bqp[2 * 48 + pidx];
        #pragma unroll
        for (int x = 0; x < 3; x++) {
            const float v = R[x*3+0]*r0 + R[x*3+1]*r1 + R[x*3+2]*r2 + T3[x];
            QP[t * 144 + pidx * 3 + x] = v;
            AP[(size_t)(h * 28 + 16 + p * 3 + x) * NTOK + t] = hwS[h] * v;
        }
    }
    // kv points: pidx = h*12+pp; pp<4 -> BP (kp), else -> VPT
    for (int pidx = wk; pidx < 144; pidx += 16) {
        const int h = pidx / 12, pp = pidx % 12;
        const float r0 = RAW[(size_t)(720 + 0 * 144 + pidx) * NTOK + t] + bkvp[0 * 144 + pidx];
        const float r1 = RAW[(size_t)(720 + 1 * 144 + pidx) * NTOK + t] + bkvp[1 * 144 + pidx];
        const float r2 = RAW[(size_t)(720 + 2 * 144 + pidx) * NTOK + t] + bkvp[2 * 144 + pidx];
        #pragma unroll
        for (int x = 0; x < 3; x++) {
            const float v = R[x*3+0]*r0 + R[x*3+1]*r1 + R[x*3+2]*r2 + T3[x];
            if (pp < 4) BP[(size_t)(h * 28 + 16 + pp * 3 + x) * NTOK + t] = v;
            else        VPT[((h * 8 + pp - 4) * 3 + x) * NTOK + t] = v;
        }
    }
    __syncthreads();
    // norms (per head, per token)
    if (wk < NH) {
        const int h = wk;
        float sq = 0.f, sk = 0.f;
        #pragma unroll
        for (int d = 0; d < 12; d++) {
            const float a = QP[t * 144 + h * 12 + d];
            sq += a * a;
            const float b = BP[(size_t)(h * 28 + 16 + d) * NTOK + t];
            sk += b * b;
        }
        RQN[h * NTOK + t] = -0.5f * hwS[h] * sq;
        CKN[h * NTOK + t] = -0.5f * hwS[h] * sk;
    }
}

// ---------------------------------------------------------------------------
// K2 (MFMA, fat blocks): one block per row i; B-frags built once; 12 j-tiles,
// double-buffered outS (1 barrier/tile); A prefetched one tile ahead.
// outS padded to 53 floats/row: BBT-epilogue read was 8-way bank conflict at
// 52 (gcd(20,32)=4); 53 -> gcd(21,32)=1 -> 2-way=free.
// C/D layout (m89-verified): col = lane&15 (=o), row = (lane>>4)*4+reg (=j).
// ---------------------------------------------------------------------------
__global__ __launch_bounds__(256) void k2_zproj_mfma(
    const float* __restrict__ z, const float* __restrict__ wb, const float* __restrict__ bb,
    const float* __restrict__ wdz, const float* __restrict__ bdz,
    float* __restrict__ BBT, uint32* __restrict__ PZB)
{
    __shared__ __align__(16) unsigned short wB[48 * 136];  // [o][k] bf16, 272B rows
    __shared__ float outS[2][64][53];                      // double-buffered [j-local][o]
    __shared__ float bbS[12], bdzS[32];

    const int tid = threadIdx.x;
    const int i   = blockIdx.x;
    const int l   = tid & 63;
    const int jt  = tid >> 6;            // wave id = 16-j sub-tile

    // stage weights as bf16, k-contiguous rows (once per block)
    for (int idx = tid; idx < 48 * 64; idx += 256) {
        const int o = idx >> 6, k2 = (idx & 63) * 2;
        float f0, f1;
        if (o < 12)      { f0 = wb[k2 * 12 + o];         f1 = wb[(k2 + 1) * 12 + o]; }
        else if (o < 44) { f0 = wdz[k2 * 32 + (o - 12)]; f1 = wdz[(k2 + 1) * 32 + (o - 12)]; }
        else             { f0 = 0.f; f1 = 0.f; }
        *(uint32*)&wB[o * 136 + k2] = pkbf(f0, f1);
    }
    if (tid < 12) bbS[tid] = bb[tid];
    else if (tid >= 32 && tid < 64) bdzS[tid - 32] = bdz[tid - 32];
    __syncthreads();

    // B fragments (once): lane: col = l&15, k = ks*32 + (l>>4)*8
    bf16x8 Bf[3][4];
    #pragma unroll
    for (int t = 0; t < 3; t++)
        #pragma unroll
        for (int ks = 0; ks < 4; ks++)
            Bf[t][ks] = *(const bf16x8*)&wB[(t * 16 + (l & 15)) * 136 + ks * 32 + (l >> 4) * 8];

    // A base for tile 0: row j = jt*16 + (l&15), k base (l>>4)*8
    const float* zb = z + ((size_t)i * NTOK + jt * 16 + (l & 15)) * CZ + (l >> 4) * 8;

    float4 pa[8];
    #pragma unroll
    for (int ks = 0; ks < 4; ks++) {
        pa[2 * ks]     = *(const float4*)&zb[ks * 32];
        pa[2 * ks + 1] = *(const float4*)&zb[ks * 32 + 4];
    }

    for (int tile = 0; tile < 12; tile++) {
        const int j0  = tile * 64;
        const int buf = tile & 1;

        // pack current tile's A into fragments
        union { uint32 u[4]; bf16x8 v; } Au[4];
        #pragma unroll
        for (int ks = 0; ks < 4; ks++) {
            Au[ks].u[0] = pkbf(pa[2 * ks].x,     pa[2 * ks].y);
            Au[ks].u[1] = pkbf(pa[2 * ks].z,     pa[2 * ks].w);
            Au[ks].u[2] = pkbf(pa[2 * ks + 1].x, pa[2 * ks + 1].y);
            Au[ks].u[3] = pkbf(pa[2 * ks + 1].z, pa[2 * ks + 1].w);
        }
        // prefetch next tile's A (overlaps MFMA + scatter + barrier + epilogue)
        if (tile < 11) {
            const float* zn = zb + (size_t)(tile + 1) * 64 * CZ;
            #pragma unroll
            for (int ks = 0; ks < 4; ks++) {
                pa[2 * ks]     = *(const float4*)&zn[ks * 32];
                pa[2 * ks + 1] = *(const float4*)&zn[ks * 32 + 4];
            }
        }

        f32x4 acc[3];
        #pragma unroll
        for (int t = 0; t < 3; t++) acc[t] = (f32x4){0.f, 0.f, 0.f, 0.f};
        #pragma unroll
        for (int ks = 0; ks < 4; ks++)
            #pragma unroll
            for (int t = 0; t < 3; t++)
                acc[t] = __builtin_amdgcn_mfma_f32_16x16x32_bf16(Au[ks].v, Bf[t][ks], acc[t], 0, 0, 0);

        // scatter D: lane l, reg v -> j_local = jt*16 + (l>>4)*4 + v, o = t*16 + (l&15)
        #pragma unroll
        for (int t = 0; t < 3; t++) {
            const int o = t * 16 + (l & 15);
            #pragma unroll
            for (int v = 0; v < 4; v++)
                outS[buf][jt * 16 + (l >> 4) * 4 + v][o] = acc[t][v];
        }
        __syncthreads();

        // BBT[i][o][j] f32 (+bias), coalesced over j
        for (int idx = tid; idx < 12 * 64; idx += 256) {
            const int o = idx >> 6, jl = idx & 63;
            BBT[((size_t)i * 12 + o) * NTOK + j0 + jl] = outS[buf][jl][o] + bbS[o];
        }
        // PZB[i][c][j-pair] bf16 (+bias), coalesced over j-pairs
        for (int idx = tid; idx < 32 * 32; idx += 256) {
            const int c = idx >> 5, jp = idx & 31;
            const float f0 = outS[buf][jp * 2][12 + c] + bdzS[c];
            const float f1 = outS[buf][jp * 2 + 1][12 + c] + bdzS[c];
            PZB[(size_t)(i * 32 + c) * 384 + (j0 >> 1) + jp] = pkbf(f0, f1);
        }
    }
}

// ---------------------------------------------------------------------------
// K3 (fused, register-resident): one block per row i, wave h = head h.
// Lane l owns logit quads j in {l*4, 256+l*4, 512+l*4} — computed in regs
// (coalesced BP reads), softmax via shfl, consumed in-place by the weighted
// sums. NO LDS, NO barriers; k3a + the 56MB LG round-trip are gone.
// ---------------------------------------------------------------------------
__global__ __launch_bounds__(768) void k3_fused(
    const float* __restrict__ AP, const float* __restrict__ BP,
    const float* __restrict__ RQN, const float* __restrict__ CKN,
    const float* __restrict__ BBT, const float* __restrict__ mask,
    const float* __restrict__ VT, const float* __restrict__ VPT,
    const uint32* __restrict__ PZB,
    float* __restrict__ O, float* __restrict__ OPT, float* __restrict__ OPAIR)
{
    const int i = blockIdx.x, tid = threadIdx.x;
    const int h = tid >> 6, l = tid & 63;   // wave = head (12 waves exactly)

    // per-head row operands (uniform within wave -> broadcast loads)
    float ap[28];
    #pragma unroll
    for (int k = 0; k < 28; k++) ap[k] = AP[(size_t)(h * 28 + k) * NTOK + i];
    const float rq = RQN[h * NTOK + i];
    const float mi = mask[i];

    // ---- logits: 3 register quads per lane
    f32x4 lg[3];
    #pragma unroll
    for (int qb = 0; qb < 3; qb++) {
        const int j4 = qb * 256 + l * 4;
        const float4 ck  = *(const float4*)&CKN[h * NTOK + j4];
        const float4 bbv = *(const float4*)&BBT[((size_t)i * 12 + h) * NTOK + j4];
        const float4 mj  = *(const float4*)&mask[j4];
        f32x4 a;
        a[0] = B_SCALE * bbv.x + rq + ck.x + INF_ * (mi * mj.x - 1.0f);
        a[1] = B_SCALE * bbv.y + rq + ck.y + INF_ * (mi * mj.y - 1.0f);
        a[2] = B_SCALE * bbv.z + rq + ck.z + INF_ * (mi * mj.z - 1.0f);
        a[3] = B_SCALE * bbv.w + rq + ck.w + INF_ * (mi * mj.w - 1.0f);
        #pragma unroll
        for (int k = 0; k < 28; k++) {
            const float4 bp = *(const float4*)&BP[(size_t)(h * 28 + k) * NTOK + j4];
            a[0] += ap[k] * bp.x; a[1] += ap[k] * bp.y;
            a[2] += ap[k] * bp.z; a[3] += ap[k] * bp.w;
        }
        lg[qb] = a;
    }

    // ---- softmax over the 12 register values x 64 lanes
    float m = -3.0e38f;
    #pragma unroll
    for (int qb = 0; qb < 3; qb++)
        #pragma unroll
        for (int v = 0; v < 4; v++) m = fmaxf(m, lg[qb][v]);
    #pragma unroll
    for (int off = 32; off >= 1; off >>= 1) m = fmaxf(m, __shfl_xor(m, off));
    float ssum = 0.0f;
    #pragma unroll
    for (int qb = 0; qb < 3; qb++)
        #pragma unroll
        for (int v = 0; v < 4; v++) {
            const float e = __expf(lg[qb][v] - m);
            lg[qb][v] = e;
            ssum += e;
        }
    #pragma unroll
    for (int off = 32; off >= 1; off >>= 1) ssum += __shfl_xor(ssum, off);
    const float inv = 1.0f / ssum;
    #pragma unroll
    for (int qb = 0; qb < 3; qb++)
        #pragma unroll
        for (int v = 0; v < 4; v++) lg[qb][v] *= inv;

    // ---- wave-cooperative weighted sums (all loads coalesced)
    #pragma unroll 2
    for (int r = 0; r < 40; r++) {
        const float4* src = (r < 16) ? (const float4*)&VT[(h * 16 + r) * NTOK]
                                     : (const float4*)&VPT[(h * 24 + (r - 16)) * NTOK];
        const float4 v0 = src[l], v1 = src[64 + l], v2 = src[128 + l];
        float acc = lg[0][0]*v0.x + lg[0][1]*v0.y + lg[0][2]*v0.z + lg[0][3]*v0.w
                  + lg[1][0]*v1.x + lg[1][1]*v1.y + lg[1][2]*v1.z + lg[1][3]*v1.w
                  + lg[2][0]*v2.x + lg[2][1]*v2.y + lg[2][2]*v2.z + lg[2][3]*v2.w;
        #pragma unroll
        for (int off = 32; off >= 1; off >>= 1) acc += __shfl_xor(acc, off);
        if (l == 0) {
            if (r < 16) O[i * 192 + h * 16 + r] = acc;
            else        OPT[i * 288 + h * 24 + (r - 16)] = acc;
        }
    }
    // o_pair: 32 bf16 rows of PZB[i][c][j] (pairs of adjacent j per u32)
    #pragma unroll 2
    for (int c = 0; c < 32; c++) {
        const uint2* src = (const uint2*)PZB + (size_t)(i * 32 + c) * 192;
        float a = 0.f;
        #pragma unroll
        for (int it = 0; it < 3; it++) {
            const uint2 u = src[it * 64 + l];
            a += lg[it][0] * bflo(u.x) + lg[it][1] * bfhi(u.x)
               + lg[it][2] * bflo(u.y) + lg[it][3] * bfhi(u.y);
        }
        #pragma unroll
        for (int off = 32; off >= 1; off >>= 1) a += __shfl_xor(a, off);
        if (l == 0) OPAIR[i * 384 + h * 32 + c] = a;
    }
}

// ---------------------------------------------------------------------------
// K4: inverse rotation + norms + concat + final linear (8 tokens/block).
// GEMM loop reads f via ds_read_b128 (4 k's per LDS instr).
// ---------------------------------------------------------------------------
#define K4T 8
__global__ __launch_bounds__(256) void k4_out(
    const float* __restrict__ O, const float* __restrict__ OPT, const float* __restrict__ OPAIR,
    const float* __restrict__ rot, const float* __restrict__ trans,
    const float* __restrict__ wout, const float* __restrict__ bout,
    float* __restrict__ out)
{
    __shared__ float f[K4T][960];
    const int n0 = blockIdx.x * K4T, tid = threadIdx.x;

    for (int idx = tid; idx < K4T * 192; idx += 256) {
        const int t = idx / 192, k = idx % 192;
        f[t][k] = O[(n0 + t) * 192 + k];
    }
    for (int idx = tid; idx < K4T * 384; idx += 256) {
        const int t = idx / 384, k = idx % 384;
        f[t][576 + k] = OPAIR[(n0 + t) * 384 + k];
    }
    for (int idx = tid; idx < K4T * 96; idx += 256) {
        const int t = idx / 96, hp = idx % 96;
        const int n = n0 + t;
        const float vx = OPT[n * 288 + hp * 3 + 0] - trans[n * 3 + 0];
        const float vy = OPT[n * 288 + hp * 3 + 1] - trans[n * 3 + 1];
        const float vz = OPT[n * 288 + hp * 3 + 2] - trans[n * 3 + 2];
        const float o0 = rot[n*9+0]*vx + rot[n*9+3]*vy + rot[n*9+6]*vz;
        const float o1 = rot[n*9+1]*vx + rot[n*9+4]*vy + rot[n*9+7]*vz;
        const float o2 = rot[n*9+2]*vx + rot[n*9+5]*vy + rot[n*9+8]*vz;
        f[t][192 + hp] = o0;
        f[t][288 + hp] = o1;
        f[t][384 + hp] = o2;
        f[t][480 + hp] = sqrtf(o0*o0 + o1*o1 + o2*o2 + EPS_);
    }
    __syncthreads();

    for (int o = tid; o < 384; o += 256) {
        float acc[K4T];
        #pragma unroll
        for (int t = 0; t < K4T; t++) acc[t] = bout[o];
        for (int kq = 0; kq < 240; kq++) {
            float4 fv[K4T];
            #pragma unroll
            for (int t = 0; t < K4T; t++) fv[t] = *(const float4*)&f[t][kq * 4];
            #pragma unroll
            for (int kk = 0; kk < 4; kk++) {
                const float wv = wout[(kq * 4 + kk) * 384 + o];
                #pragma unroll
                for (int t = 0; t < K4T; t++) {
                    const float fe = (kk == 0) ? fv[t].x : (kk == 1) ? fv[t].y
                                   : (kk == 2) ? fv[t].z : fv[t].w;
                    acc[t] += fe * wv;
                }
            }
        }
        #pragma unroll
        for (int t = 0; t < K4T; t++) out[(n0 + t) * 384 + o] = acc[t];
    }
}

// ---------------------------------------------------------------------------
extern "C" void kernel_launch(void* const* d_in, const int* in_sizes, int n_in,
                              void* d_out, int out_size, void* d_ws, size_t ws_size,
                              hipStream_t stream) {
    (void)in_sizes; (void)n_in; (void)out_size; (void)ws_size;
    const float* s     = (const float*)d_in[0];
    const float* z     = (const float*)d_in[1];
    const float* rot   = (const float*)d_in[2];
    const float* trans = (const float*)d_in[3];
    const float* mask  = (const float*)d_in[4];
    const float* wq    = (const float*)d_in[5];
    const float* bq    = (const float*)d_in[6];
    const float* wkv   = (const float*)d_in[7];
    const float* bkv   = (const float*)d_in[8];
    const float* wqp   = (const float*)d_in[9];
    const float* bqp   = (const float*)d_in[10];
    const float* wkvp  = (const float*)d_in[11];
    const float* bkvp  = (const float*)d_in[12];
    const float* wb    = (const float*)d_in[13];
    const float* bb    = (const float*)d_in[14];
    const float* wdz   = (const float*)d_in[15];
    const float* bdz   = (const float*)d_in[16];
    const float* hwts  = (const float*)d_in[17];
    const float* wout  = (const float*)d_in[18];
    const float* bout  = (const float*)d_in[19];
    float* out = (float*)d_out;

    float* ws = (float*)d_ws;
    float* Q     = ws;                       // 147456 (unused, kept for layout)
    float* KT    = Q     + 147456;           // 147456 (unused)
    float* VT    = KT    + 147456;           // 147456
    float* QP    = VT    + 147456;           // 110592
    float* KPT   = QP    + 110592;           // 110592 (unused)
    float* VPT   = KPT   + 110592;           // 221184
    float* O     = VPT   + 221184;           // 147456
    float* OPT   = O     + 147456;           // 221184
    float* OPAIR = OPT   + 221184;           // 294912
    float* BBT   = OPAIR + 294912;           // 7,077,888 floats (28.3 MB)
    uint32* PZB  = (uint32*)(BBT + 7077888); // 768*32*384 u32 (37.7 MB)
    float* AP    = BBT + 7077888 + 9437184;  // 12*28*768 = 258048
    float* BP    = AP  + 258048;             // 258048
    float* RQN   = BP  + 258048;             // 9216
    float* CKN   = RQN + 9216;               // 9216
    float* RAW = BBT;   // aliases BBT: dead before k2 runs

    hipLaunchKernelGGL(k1a_gemm, dim3(NTOK / 64, 1152 / 64), dim3(256), 0, stream,
                       s, wq, wkv, wqp, wkvp, RAW);
    hipLaunchKernelGGL(k1b_finish, dim3(NTOK / 16), dim3(256), 0, stream,
                       RAW, rot, trans, bq, bkv, bqp, bkvp, hwts,
                       VT, QP, VPT, AP, BP, RQN, CKN);
    hipLaunchKernelGGL(k2_zproj_mfma, dim3(NTOK), dim3(256), 0, stream,
                       z, wb, bb, wdz, bdz, BBT, PZB);
    hipLaunchKernelGGL(k3_fused, dim3(NTOK), dim3(768), 0, stream,
                       AP, BP, RQN, CKN, BBT, mask, VT, VPT, PZB,
                       O, OPT, OPAIR);
    hipLaunchKernelGGL(k4_out, dim3(NTOK / K4T), dim3(256), 0, stream,
                       O, OPT, OPAIR, rot, trans, wout, bout, out);
}